// Round 1
// baseline (3958.834 us; speedup 1.0000x reference)
//
#include <hip/hip_runtime.h>
#include <cstdint>
#include <cstddef>

#define LSEQ   1024
#define BATCH  32
#define NFEAT  512
#define DMODEL 512
#define DINNER 1024
#define DSTATE 16
#define DTRANK 32
#define NCLASS 40
#define MROWS  (BATCH * LSEQ)   // 32768

typedef unsigned short u16;
typedef __attribute__((ext_vector_type(8))) __bf16 bf16x8;
typedef __attribute__((ext_vector_type(4))) float f32x4;
typedef __attribute__((ext_vector_type(8))) unsigned short u16x8;

__device__ __forceinline__ u16 f2bf(float x) {
    union { float f; unsigned u; } v; v.f = x;
    unsigned r = v.u + 0x7fffu + ((v.u >> 16) & 1u);   // round-to-nearest-even
    return (u16)(r >> 16);
}
__device__ __forceinline__ float bf2f(u16 h) {
    union { unsigned u; float f; } v; v.u = ((unsigned)h) << 16;
    return v.f;
}

#define GLL16(g, l) __builtin_amdgcn_global_load_lds( \
    (__attribute__((address_space(1))) void*)(g),     \
    (__attribute__((address_space(3))) void*)(l), 16, 0, 0)

// ---------------------------------------------------------------------------
// C[M,N] = A[M,K](bf16,lda) * B[N,K](bf16,ldb)^T  (+bias) (+softplus) ;
// OUT_BF16: store bf16; ACCUM: f32 +=. 128x128 tile, BK=32, 256 thr (4 waves).
// mfma_f32_16x16x32_bf16: A frag A[m=lane&15][k=(lane>>4)*8+j];
// C/D: col=lane&15, row=(lane>>4)*4+reg  (HW-verified layouts).
// ---------------------------------------------------------------------------
template<int OUT_BF16, int ACCUM, int ACT>
__global__ __launch_bounds__(256) void gemm_bt(
    const u16* __restrict__ A, int lda,
    const u16* __restrict__ B, int ldb,
    void* __restrict__ Cv, int ldc,
    const float* __restrict__ bias, int K)
{
    __shared__ __align__(16) u16 As[128 * 32];
    __shared__ __align__(16) u16 Bs[128 * 32];
    const int tid  = threadIdx.x;
    const int m0   = blockIdx.x * 128;
    const int n0   = blockIdx.y * 128;
    const int r0   = tid >> 2;            // staging row (0..63), +64 for job 1
    const int c0   = (tid & 3) << 3;      // staging k-chunk (0,8,16,24)
    const int lane = tid & 63;
    const int wave = tid >> 6;
    const int wr   = (wave >> 1) << 6;    // wave row offset in tile
    const int wc   = (wave & 1) << 6;     // wave col offset in tile
    const int frow = lane & 15;
    const int fk   = (lane >> 4) << 3;
    const int quad = lane >> 4;

    const u16* Ap0 = A + (size_t)(m0 + r0) * lda + c0;
    const u16* Ap1 = Ap0 + (size_t)64 * lda;
    const u16* Bp0 = B + (size_t)(n0 + r0) * ldb + c0;
    const u16* Bp1 = Bp0 + (size_t)64 * ldb;
    u16* lA0 = As + tid * 8;  u16* lA1 = As + (tid + 256) * 8;
    u16* lB0 = Bs + tid * 8;  u16* lB1 = Bs + (tid + 256) * 8;

    f32x4 acc[4][4];
#pragma unroll
    for (int i = 0; i < 4; ++i)
#pragma unroll
        for (int j = 0; j < 4; ++j) acc[i][j] = (f32x4){0.f, 0.f, 0.f, 0.f};

    for (int k0 = 0; k0 < K; k0 += 32) {
        GLL16(Ap0 + k0, lA0);
        GLL16(Ap1 + k0, lA1);
        GLL16(Bp0 + k0, lB0);
        GLL16(Bp1 + k0, lB1);
        __syncthreads();
        bf16x8 af[4], bfr[4];
#pragma unroll
        for (int i = 0; i < 4; ++i) {
            af[i]  = *(const bf16x8*)(As + (wr + i * 16 + frow) * 32 + fk);
            bfr[i] = *(const bf16x8*)(Bs + (wc + i * 16 + frow) * 32 + fk);
        }
#pragma unroll
        for (int i = 0; i < 4; ++i)
#pragma unroll
            for (int j = 0; j < 4; ++j)
                acc[i][j] = __builtin_amdgcn_mfma_f32_16x16x32_bf16(
                    af[i], bfr[j], acc[i][j], 0, 0, 0);
        __syncthreads();
    }

    float bv[4];
#pragma unroll
    for (int j = 0; j < 4; ++j)
        bv[j] = bias ? bias[n0 + wc + j * 16 + frow] : 0.f;

#pragma unroll
    for (int i = 0; i < 4; ++i) {
#pragma unroll
        for (int r = 0; r < 4; ++r) {
            size_t row = (size_t)(m0 + wr + i * 16 + quad * 4 + r);
#pragma unroll
            for (int j = 0; j < 4; ++j) {
                size_t cidx = row * (size_t)ldc + (size_t)(n0 + wc + j * 16 + frow);
                float v = acc[i][j][r] + bv[j];
                if (ACT == 1) v = (v > 15.f) ? v : log1pf(expf(v));  // softplus
                if (OUT_BF16)      ((u16*)Cv)[cidx] = f2bf(v);
                else if (ACCUM)    ((float*)Cv)[cidx] += v;
                else               ((float*)Cv)[cidx] = v;
            }
        }
    }
}

// --------------------------- elementwise / prep ----------------------------

__global__ __launch_bounds__(256) void cvt_bf16_kernel(
    const float* __restrict__ src, u16* __restrict__ dst, int n4)
{
    int i = blockIdx.x * 256 + threadIdx.x;
    if (i >= n4) return;
    float4 v = ((const float4*)src)[i];
    ushort4 o; o.x = f2bf(v.x); o.y = f2bf(v.y); o.z = f2bf(v.z); o.w = f2bf(v.w);
    ((ushort4*)dst)[i] = o;
}

// x_proj_w (2,64,1024) f32 -> (2,128,1024) bf16, rows 64..127 zero
__global__ __launch_bounds__(256) void pad_xpw_kernel(
    const float* __restrict__ src, u16* __restrict__ dst)
{
    int i  = blockIdx.x * 256 + threadIdx.x;   // per float4; total 2*128*1024/4
    int k4 = i & 255;
    int r  = (i >> 8) & 127;
    int l  = i >> 15;
    ushort4 o;
    if (r < 64) {
        float4 v = ((const float4*)(src + ((size_t)l * 64 + r) * DINNER))[k4];
        o.x = f2bf(v.x); o.y = f2bf(v.y); o.z = f2bf(v.z); o.w = f2bf(v.w);
    } else { o.x = 0; o.y = 0; o.z = 0; o.w = 0; }
    ((ushort4*)dst)[i] = o;
}

// gathered_emb[m,:] = bf16(embeddings[sequence[m],:])
__global__ __launch_bounds__(256) void gather_kernel(
    const int* __restrict__ seq, const float* __restrict__ emb, u16* __restrict__ g)
{
    int i   = blockIdx.x * 256 + threadIdx.x;  // per float4; total MROWS*128
    int row = i >> 7, c = i & 127;
    int node = seq[row];
    float4 v = ((const float4*)(emb + (size_t)node * NFEAT))[c];
    ushort4 o; o.x = f2bf(v.x); o.y = f2bf(v.y); o.z = f2bf(v.z); o.w = f2bf(v.w);
    ((ushort4*)g)[i] = o;
}

// zi = scale * x / (||x||/sqrt(512) + 1e-8), one wave per row
__global__ __launch_bounds__(256) void rmsnorm_kernel(
    const float* __restrict__ x, const float* __restrict__ scale, u16* __restrict__ o)
{
    int wave = threadIdx.x >> 6, lane = threadIdx.x & 63;
    size_t row = (size_t)blockIdx.x * 4 + wave;
    const float4* xr = (const float4*)(x + row * DMODEL);
    float4 v0 = xr[lane], v1 = xr[lane + 64];
    float ss = v0.x*v0.x + v0.y*v0.y + v0.z*v0.z + v0.w*v0.w
             + v1.x*v1.x + v1.y*v1.y + v1.z*v1.z + v1.w*v1.w;
#pragma unroll
    for (int off = 32; off; off >>= 1) ss += __shfl_xor(ss, off, 64);
    float inv = 1.f / (sqrtf(ss * (1.f / DMODEL)) + 1e-8f);
    const float4* sc = (const float4*)scale;
    float4 s0 = sc[lane], s1 = sc[lane + 64];
    ushort4 o0, o1;
    o0.x = f2bf(v0.x * s0.x * inv); o0.y = f2bf(v0.y * s0.y * inv);
    o0.z = f2bf(v0.z * s0.z * inv); o0.w = f2bf(v0.w * s0.w * inv);
    o1.x = f2bf(v1.x * s1.x * inv); o1.y = f2bf(v1.y * s1.y * inv);
    o1.z = f2bf(v1.z * s1.z * inv); o1.w = f2bf(v1.w * s1.w * inv);
    ushort4* op = (ushort4*)(o + row * DMODEL);
    op[lane] = o0; op[lane + 64] = o1;
}

// causal depthwise conv (window 4) + bias + silu; xin = xz[:, 0:DINNER]
__global__ __launch_bounds__(256) void conv_silu_kernel(
    const u16* __restrict__ xz, const float* __restrict__ w,
    const float* __restrict__ cbv, u16* __restrict__ xc)
{
    int idx = blockIdx.x * 256 + threadIdx.x;  // 0 .. MROWS*DINNER-1
    int d = idx & (DINNER - 1);
    int r = idx >> 10;                          // global row (b*L + l)
    int l = r & (LSEQ - 1);
    float acc = cbv[d];
    const float* wd = w + d * 4;
#pragma unroll
    for (int j = 0; j < 4; ++j) {
        int ls = l - 3 + j;
        if (ls >= 0) acc += wd[j] * bf2f(xz[(size_t)(r - 3 + j) * (2 * DINNER) + d]);
    }
    float s = acc / (1.f + expf(-acc));         // silu
    xc[idx] = f2bf(s);
}

// selective scan: one thread per (b,d); h[16] in regs; gating fused
__global__ __launch_bounds__(256) void scan_kernel(
    const u16* __restrict__ delta, const u16* __restrict__ xconv,
    const u16* __restrict__ xz, const u16* __restrict__ xdbl,
    const float* __restrict__ alog, const float* __restrict__ Dvec,
    u16* __restrict__ ybuf)
{
    int t = blockIdx.x * 256 + threadIdx.x;
    int d = t & (DINNER - 1);
    int b = t >> 10;
    float a2[DSTATE];
#pragma unroll
    for (int s = 0; s < DSTATE; ++s)
        a2[s] = -expf(alog[d * DSTATE + s]) * 1.44269504f;  // A * log2(e)
    float Dd = Dvec[d];
    float h[DSTATE];
#pragma unroll
    for (int s = 0; s < DSTATE; ++s) h[s] = 0.f;

    size_t rb = (size_t)b * LSEQ;
    const u16* pd = delta + rb * DINNER + d;
    const u16* px = xconv + rb * DINNER + d;
    const u16* pz = xz + rb * (2 * DINNER) + DINNER + d;
    const u16* pB = xdbl + rb * 128 + 32;
    u16* py = ybuf + rb * DINNER + d;

    for (int l = 0; l < LSEQ; ++l) {
        float dt = bf2f(*pd);
        float xv = bf2f(*px);
        float zv = bf2f(*pz);
        u16x8 q0 = *(const u16x8*)(pB);        // Bm[0..7]
        u16x8 q1 = *(const u16x8*)(pB + 8);    // Bm[8..15]
        u16x8 q2 = *(const u16x8*)(pB + 16);   // Cm[0..7]
        u16x8 q3 = *(const u16x8*)(pB + 24);   // Cm[8..15]
        float dx = dt * xv;
        float yv = 0.f;
#pragma unroll
        for (int s = 0; s < 8; ++s) {
            float dA = exp2f(dt * a2[s]);
            h[s] = h[s] * dA + dx * bf2f(q0[s]);
            yv += h[s] * bf2f(q2[s]);
        }
#pragma unroll
        for (int s = 8; s < 16; ++s) {
            float dA = exp2f(dt * a2[s]);
            h[s] = h[s] * dA + dx * bf2f(q1[s - 8]);
            yv += h[s] * bf2f(q3[s - 8]);
        }
        yv += Dd * xv;
        float sig = 1.f / (1.f + expf(-zv));
        yv *= zv * sig;                         // y * silu(z)
        *py = f2bf(yv);
        pd += DINNER; px += DINNER; pz += 2 * DINNER; pB += 128; py += DINNER;
    }
}

// masked-mean partials: grid (8 chunks, 32 b)
__global__ __launch_bounds__(256) void pool_partial_kernel(
    const float* __restrict__ subg, const float* __restrict__ incl,
    float* __restrict__ part, float* __restrict__ msump)
{
    int chunk = blockIdx.x, b = blockIdx.y, tid = threadIdx.x;
    float a0 = 0.f, a1 = 0.f, ms = 0.f;
    for (int l0 = 0; l0 < 128; ++l0) {
        int l = chunk * 128 + l0;
        float m = incl[b * LSEQ + l];
        const float* row = subg + ((size_t)b * LSEQ + l) * DMODEL;
        a0 += m * row[tid];
        a1 += m * row[tid + 256];
        ms += m;
    }
    int pi = (b * 8 + chunk) * DMODEL;
    part[pi + tid] = a0;
    part[pi + tid + 256] = a1;
    if (tid == 0) msump[b * 8 + chunk] = ms;
}

__global__ __launch_bounds__(256) void fc2_kernel(
    const float* __restrict__ part, const float* __restrict__ msump,
    const float* __restrict__ fc2w, const float* __restrict__ fc2b,
    float* __restrict__ out)
{
    int b = blockIdx.x, tid = threadIdx.x;
    __shared__ float pooled[DMODEL];
    float s0 = 0.f, s1 = 0.f, ms = 0.f;
#pragma unroll
    for (int c = 0; c < 8; ++c) {
        s0 += part[(b * 8 + c) * DMODEL + tid];
        s1 += part[(b * 8 + c) * DMODEL + tid + 256];
        ms += msump[b * 8 + c];
    }
    float inv = 1.f / (ms + 1e-5f);
    pooled[tid] = s0 * inv; pooled[tid + 256] = s1 * inv;
    __syncthreads();
    int wave = tid >> 6, lane = tid & 63;
    for (int c = wave; c < NCLASS; c += 4) {
        float s = 0.f;
#pragma unroll
        for (int k = lane; k < DMODEL; k += 64) s += pooled[k] * fc2w[c * DMODEL + k];
#pragma unroll
        for (int off = 32; off; off >>= 1) s += __shfl_xor(s, off, 64);
        if (lane == 0) out[b * NCLASS + c] = s + fc2b[c];
    }
}

// ---------------------------------------------------------------------------

extern "C" void kernel_launch(void* const* d_in, const int* in_sizes, int n_in,
                              void* d_out, int out_size, void* d_ws, size_t ws_size,
                              hipStream_t stream)
{
    (void)in_sizes; (void)n_in; (void)out_size; (void)ws_size;
    const int*   seq    = (const int*)  d_in[0];
    const float* incl   = (const float*)d_in[1];
    const float* emb    = (const float*)d_in[2];
    const float* fc1w   = (const float*)d_in[3];
    const float* fc1b   = (const float*)d_in[4];
    const float* fc2w   = (const float*)d_in[5];
    const float* fc2b   = (const float*)d_in[6];
    const float* nscale = (const float*)d_in[7];
    const float* ipw    = (const float*)d_in[8];
    const float* cw     = (const float*)d_in[9];
    const float* cbv    = (const float*)d_in[10];
    const float* xpw    = (const float*)d_in[11];
    const float* dtw    = (const float*)d_in[12];
    const float* dtb    = (const float*)d_in[13];
    const float* alog   = (const float*)d_in[14];
    const float* Dvec   = (const float*)d_in[15];
    const float* opw    = (const float*)d_in[16];
    float* outp = (float*)d_out;

    char* w = (char*)d_ws;
    size_t off = 0;
    auto take = [&](size_t bytes) {
        char* p = w + off; off += (bytes + 255) & ~(size_t)255; return p;
    };
    float* subg  = (float*)take((size_t)MROWS * DMODEL * 4);       // fp32 residual stream
    u16*   zi    = (u16*)  take((size_t)MROWS * DMODEL * 2);       // rmsnorm out
    u16*   xzb   = (u16*)  take((size_t)MROWS * 2 * DINNER * 2);   // in_proj out (xin|z)
    u16*   xconv = (u16*)  take((size_t)MROWS * DINNER * 2);       // conv+silu out
    u16*   xdbl  = (u16*)  take((size_t)MROWS * 128 * 2);          // x_proj out (pad 128)
    u16*   delta = (u16*)  take((size_t)MROWS * DINNER * 2);       // softplus(dt_proj)
    u16*   ybuf  = (u16*)  take((size_t)MROWS * DINNER * 2);       // scan out (gated)
    u16*   wip   = (u16*)  take((size_t)2 * 2 * DINNER * DMODEL * 2);
    u16*   wop   = (u16*)  take((size_t)2 * DMODEL * DINNER * 2);
    u16*   wxp   = (u16*)  take((size_t)2 * 128 * DINNER * 2);
    u16*   wdt   = (u16*)  take((size_t)2 * DINNER * DTRANK * 2);
    u16*   wfc1  = (u16*)  take((size_t)DMODEL * NFEAT * 2);
    float* part  = (float*)take((size_t)BATCH * 8 * DMODEL * 4);
    float* msump = (float*)take((size_t)BATCH * 8 * 4);
    u16*   gemb  = (u16*)delta;  // alias: gathered emb consumed before delta written

    // weight prep (ws re-poisoned every call, so redo each call)
    cvt_bf16_kernel<<<(DMODEL * NFEAT / 4 + 255) / 256, 256, 0, stream>>>(fc1w, wfc1, DMODEL * NFEAT / 4);
    cvt_bf16_kernel<<<(2 * 2 * DINNER * DMODEL / 4 + 255) / 256, 256, 0, stream>>>(ipw, wip, 2 * 2 * DINNER * DMODEL / 4);
    cvt_bf16_kernel<<<(2 * DMODEL * DINNER / 4 + 255) / 256, 256, 0, stream>>>(opw, wop, 2 * DMODEL * DINNER / 4);
    cvt_bf16_kernel<<<(2 * DINNER * DTRANK / 4 + 255) / 256, 256, 0, stream>>>(dtw, wdt, 2 * DINNER * DTRANK / 4);
    pad_xpw_kernel<<<(2 * 128 * DINNER / 4) / 256, 256, 0, stream>>>(xpw, wxp);
    gather_kernel<<<MROWS * (NFEAT / 4) / 256, 256, 0, stream>>>(seq, emb, gemb);

    // subg = gathered_emb @ fc1_w^T + fc1_b   (f32 out)
    gemm_bt<0, 0, 0><<<dim3(MROWS / 128, DMODEL / 128), 256, 0, stream>>>(
        gemb, NFEAT, wfc1, NFEAT, subg, DMODEL, fc1b, NFEAT);

    for (int i = 0; i < 2; ++i) {
        rmsnorm_kernel<<<MROWS / 4, 256, 0, stream>>>(subg, nscale + i * DMODEL, zi);
        // xz = zi @ in_proj_w^T  (bf16 out, N=2048)
        gemm_bt<1, 0, 0><<<dim3(MROWS / 128, 2 * DINNER / 128), 256, 0, stream>>>(
            zi, DMODEL, wip + (size_t)i * 2 * DINNER * DMODEL, DMODEL,
            xzb, 2 * DINNER, nullptr, DMODEL);
        conv_silu_kernel<<<MROWS * DINNER / 256, 256, 0, stream>>>(
            xzb, cw + i * DINNER * 4, cbv + i * DINNER, xconv);
        // x_dbl = xconv @ x_proj_w^T (N padded to 128)
        gemm_bt<1, 0, 0><<<dim3(MROWS / 128, 1), 256, 0, stream>>>(
            xconv, DINNER, wxp + (size_t)i * 128 * DINNER, DINNER,
            xdbl, 128, nullptr, DINNER);
        // delta = softplus(dt @ dt_proj_w^T + dt_proj_b)  (K=32)
        gemm_bt<1, 0, 1><<<dim3(MROWS / 128, DINNER / 128), 256, 0, stream>>>(
            xdbl, 128, wdt + (size_t)i * DINNER * DTRANK, DTRANK,
            delta, DINNER, dtb + i * DINNER, DTRANK);
        scan_kernel<<<MROWS / 256, 256, 0, stream>>>(
            delta, xconv, xzb, xdbl, alog + i * DINNER * DSTATE, Dvec + i * DINNER, ybuf);
        // subg += y @ out_proj_w^T  (f32 accumulate)
        gemm_bt<0, 1, 0><<<dim3(MROWS / 128, DMODEL / 128), 256, 0, stream>>>(
            ybuf, DINNER, wop + (size_t)i * DMODEL * DINNER, DINNER,
            subg, DMODEL, nullptr, DINNER);
    }

    pool_partial_kernel<<<dim3(8, BATCH), 256, 0, stream>>>(subg, incl, part, msump);
    fc2_kernel<<<BATCH, 256, 0, stream>>>(part, msump, fc2w, fc2b, outp);
}

// Round 2
// 3303.343 us; speedup vs baseline: 1.1984x; 1.1984x over previous
//
#include <hip/hip_runtime.h>
#include <cstdint>
#include <cstddef>

#define LSEQ   1024
#define BATCH  32
#define NFEAT  512
#define DMODEL 512
#define DINNER 1024
#define DSTATE 16
#define DTRANK 32
#define NCLASS 40
#define MROWS  (BATCH * LSEQ)   // 32768

typedef unsigned short u16;
typedef __attribute__((ext_vector_type(8))) __bf16 bf16x8;
typedef __attribute__((ext_vector_type(4))) float f32x4;

__device__ __forceinline__ u16 f2bf(float x) {
    union { float f; unsigned u; } v; v.f = x;
    unsigned r = v.u + 0x7fffu + ((v.u >> 16) & 1u);   // round-to-nearest-even
    return (u16)(r >> 16);
}
__device__ __forceinline__ float bf2f(u16 h) {
    union { unsigned u; float f; } v; v.u = ((unsigned)h) << 16;
    return v.f;
}

#define GLL16(g, l) __builtin_amdgcn_global_load_lds( \
    (__attribute__((address_space(1))) void*)(g),     \
    (__attribute__((address_space(3))) void*)(l), 16, 0, 0)

// ---------------------------------------------------------------------------
// C[M,N] = A[M,K](bf16,lda) * B[N,K](bf16,ldb)^T  (+bias) (+softplus) ;
// OUT_BF16: store bf16; ACCUM: f32 +=. 128x128 tile, BK=32, 256 thr (4 waves).
// ---------------------------------------------------------------------------
template<int OUT_BF16, int ACCUM, int ACT>
__global__ __launch_bounds__(256) void gemm_bt(
    const u16* __restrict__ A, int lda,
    const u16* __restrict__ B, int ldb,
    void* __restrict__ Cv, int ldc,
    const float* __restrict__ bias, int K)
{
    __shared__ __align__(16) u16 As[128 * 32];
    __shared__ __align__(16) u16 Bs[128 * 32];
    const int tid  = threadIdx.x;
    const int m0   = blockIdx.x * 128;
    const int n0   = blockIdx.y * 128;
    const int r0   = tid >> 2;            // staging row (0..63), +64 for job 1
    const int c0   = (tid & 3) << 3;      // staging k-chunk (0,8,16,24)
    const int lane = tid & 63;
    const int wave = tid >> 6;
    const int wr   = (wave >> 1) << 6;    // wave row offset in tile
    const int wc   = (wave & 1) << 6;     // wave col offset in tile
    const int frow = lane & 15;
    const int fk   = (lane >> 4) << 3;
    const int quad = lane >> 4;

    const u16* Ap0 = A + (size_t)(m0 + r0) * lda + c0;
    const u16* Ap1 = Ap0 + (size_t)64 * lda;
    const u16* Bp0 = B + (size_t)(n0 + r0) * ldb + c0;
    const u16* Bp1 = Bp0 + (size_t)64 * ldb;
    u16* lA0 = As + tid * 8;  u16* lA1 = As + (tid + 256) * 8;
    u16* lB0 = Bs + tid * 8;  u16* lB1 = Bs + (tid + 256) * 8;

    f32x4 acc[4][4];
#pragma unroll
    for (int i = 0; i < 4; ++i)
#pragma unroll
        for (int j = 0; j < 4; ++j) acc[i][j] = (f32x4){0.f, 0.f, 0.f, 0.f};

    for (int k0 = 0; k0 < K; k0 += 32) {
        GLL16(Ap0 + k0, lA0);
        GLL16(Ap1 + k0, lA1);
        GLL16(Bp0 + k0, lB0);
        GLL16(Bp1 + k0, lB1);
        __syncthreads();
        bf16x8 af[4], bfr[4];
#pragma unroll
        for (int i = 0; i < 4; ++i) {
            af[i]  = *(const bf16x8*)(As + (wr + i * 16 + frow) * 32 + fk);
            bfr[i] = *(const bf16x8*)(Bs + (wc + i * 16 + frow) * 32 + fk);
        }
#pragma unroll
        for (int i = 0; i < 4; ++i)
#pragma unroll
            for (int j = 0; j < 4; ++j)
                acc[i][j] = __builtin_amdgcn_mfma_f32_16x16x32_bf16(
                    af[i], bfr[j], acc[i][j], 0, 0, 0);
        __syncthreads();
    }

    float bv[4];
#pragma unroll
    for (int j = 0; j < 4; ++j)
        bv[j] = bias ? bias[n0 + wc + j * 16 + frow] : 0.f;

#pragma unroll
    for (int i = 0; i < 4; ++i) {
#pragma unroll
        for (int r = 0; r < 4; ++r) {
            size_t row = (size_t)(m0 + wr + i * 16 + quad * 4 + r);
#pragma unroll
            for (int j = 0; j < 4; ++j) {
                size_t cidx = row * (size_t)ldc + (size_t)(n0 + wc + j * 16 + frow);
                float v = acc[i][j][r] + bv[j];
                if (ACT == 1) v = (v > 15.f) ? v : log1pf(expf(v));  // softplus
                if (OUT_BF16)      ((u16*)Cv)[cidx] = f2bf(v);
                else if (ACCUM)    ((float*)Cv)[cidx] += v;
                else               ((float*)Cv)[cidx] = v;
            }
        }
    }
}

// --------------------------- elementwise / prep ----------------------------

__global__ __launch_bounds__(256) void cvt_bf16_kernel(
    const float* __restrict__ src, u16* __restrict__ dst, int n4)
{
    int i = blockIdx.x * 256 + threadIdx.x;
    if (i >= n4) return;
    float4 v = ((const float4*)src)[i];
    ushort4 o; o.x = f2bf(v.x); o.y = f2bf(v.y); o.z = f2bf(v.z); o.w = f2bf(v.w);
    ((ushort4*)dst)[i] = o;
}

// x_proj_w (2,64,1024) f32 -> (2,128,1024) bf16, rows 64..127 zero
__global__ __launch_bounds__(256) void pad_xpw_kernel(
    const float* __restrict__ src, u16* __restrict__ dst)
{
    int i  = blockIdx.x * 256 + threadIdx.x;   // per float4; total 2*128*1024/4
    int k4 = i & 255;
    int r  = (i >> 8) & 127;
    int l  = i >> 15;
    ushort4 o;
    if (r < 64) {
        float4 v = ((const float4*)(src + ((size_t)l * 64 + r) * DINNER))[k4];
        o.x = f2bf(v.x); o.y = f2bf(v.y); o.z = f2bf(v.z); o.w = f2bf(v.w);
    } else { o.x = 0; o.y = 0; o.z = 0; o.w = 0; }
    ((ushort4*)dst)[i] = o;
}

// gathered_emb[m,:] = bf16(embeddings[sequence[m],:])
__global__ __launch_bounds__(256) void gather_kernel(
    const int* __restrict__ seq, const float* __restrict__ emb, u16* __restrict__ g)
{
    int i   = blockIdx.x * 256 + threadIdx.x;  // per float4; total MROWS*128
    int row = i >> 7, c = i & 127;
    int node = seq[row];
    float4 v = ((const float4*)(emb + (size_t)node * NFEAT))[c];
    ushort4 o; o.x = f2bf(v.x); o.y = f2bf(v.y); o.z = f2bf(v.z); o.w = f2bf(v.w);
    ((ushort4*)g)[i] = o;
}

// zi = scale * x / (||x||/sqrt(512) + 1e-8), one wave per row
__global__ __launch_bounds__(256) void rmsnorm_kernel(
    const float* __restrict__ x, const float* __restrict__ scale, u16* __restrict__ o)
{
    int wave = threadIdx.x >> 6, lane = threadIdx.x & 63;
    size_t row = (size_t)blockIdx.x * 4 + wave;
    const float4* xr = (const float4*)(x + row * DMODEL);
    float4 v0 = xr[lane], v1 = xr[lane + 64];
    float ss = v0.x*v0.x + v0.y*v0.y + v0.z*v0.z + v0.w*v0.w
             + v1.x*v1.x + v1.y*v1.y + v1.z*v1.z + v1.w*v1.w;
#pragma unroll
    for (int off = 32; off; off >>= 1) ss += __shfl_xor(ss, off, 64);
    float inv = 1.f / (sqrtf(ss * (1.f / DMODEL)) + 1e-8f);
    const float4* sc = (const float4*)scale;
    float4 s0 = sc[lane], s1 = sc[lane + 64];
    ushort4 o0, o1;
    o0.x = f2bf(v0.x * s0.x * inv); o0.y = f2bf(v0.y * s0.y * inv);
    o0.z = f2bf(v0.z * s0.z * inv); o0.w = f2bf(v0.w * s0.w * inv);
    o1.x = f2bf(v1.x * s1.x * inv); o1.y = f2bf(v1.y * s1.y * inv);
    o1.z = f2bf(v1.z * s1.z * inv); o1.w = f2bf(v1.w * s1.w * inv);
    ushort4* op = (ushort4*)(o + row * DMODEL);
    op[lane] = o0; op[lane + 64] = o1;
}

// causal depthwise conv (window 4) + bias + silu on x-half;
// ALSO: z-half of xz is replaced in-place by silu(z) (consumed only by scan).
__global__ __launch_bounds__(256) void conv_silu_kernel(
    const u16* __restrict__ xzc, u16* __restrict__ xzm,
    const float* __restrict__ w, const float* __restrict__ cbv,
    u16* __restrict__ xc)
{
    int idx = blockIdx.x * 256 + threadIdx.x;  // 0 .. MROWS*DINNER-1
    int d = idx & (DINNER - 1);
    int r = idx >> 10;                          // global row (b*L + l)
    int l = r & (LSEQ - 1);
    float acc = cbv[d];
    const float* wd = w + d * 4;
#pragma unroll
    for (int j = 0; j < 4; ++j) {
        int ls = l - 3 + j;
        if (ls >= 0) acc += wd[j] * bf2f(xzc[(size_t)(r - 3 + j) * (2 * DINNER) + d]);
    }
    float s = acc / (1.f + expf(-acc));         // silu
    xc[idx] = f2bf(s);
    // silu(z) in place
    size_t zi = (size_t)r * (2 * DINNER) + DINNER + d;
    float zv = bf2f(xzc[zi]);
    xzm[zi] = f2bf(zv / (1.f + expf(-zv)));
}

// selective scan v2: 16 lanes per (b,d) channel, one state per lane.
// y reduced via shfl_xor over the 16-lane group; lane s==0 gates + writes.
__global__ __launch_bounds__(256) void scan_kernel(
    const u16* __restrict__ delta, const u16* __restrict__ xconv,
    const u16* __restrict__ zsil, const u16* __restrict__ xdbl,
    const float* __restrict__ alog, const float* __restrict__ Dvec,
    u16* __restrict__ ybuf)
{
    int t = blockIdx.x * 256 + threadIdx.x;     // 0 .. B*DINNER*16-1
    int s = t & (DSTATE - 1);
    int c = t >> 4;                              // channel id: b*DINNER + d
    int d = c & (DINNER - 1);
    int b = c >> 10;

    float a2 = -expf(alog[d * DSTATE + s]) * 1.44269504f;  // A[s] * log2(e)
    float Dd = Dvec[d];
    float h  = 0.f;

    size_t rb = (size_t)b * LSEQ;
    const u16* pd  = delta + rb * DINNER + d;
    const u16* px  = xconv + rb * DINNER + d;
    const u16* pz  = zsil + rb * (2 * DINNER) + DINNER + d;  // silu(z), in xzb z-half
    const u16* pB  = xdbl + rb * 128 + 32 + s;               // Bm[s]; Cm[s] at +16
    u16* py = ybuf + rb * DINNER + d;

    for (int l = 0; l < LSEQ; ++l) {
        float dt = bf2f(*pd);
        float xv = bf2f(*px);
        float Bv = bf2f(pB[0]);
        float Cv = bf2f(pB[16]);
        float dA = __builtin_amdgcn_exp2f(dt * a2);
        h = h * dA + (dt * xv) * Bv;
        float p = h * Cv;
        p += __shfl_xor(p, 1, 64);
        p += __shfl_xor(p, 2, 64);
        p += __shfl_xor(p, 4, 64);
        p += __shfl_xor(p, 8, 64);
        if (s == 0) {
            float zs = bf2f(*pz);
            *py = f2bf((p + Dd * xv) * zs);
        }
        pd += DINNER; px += DINNER; pz += 2 * DINNER; pB += 128; py += DINNER;
    }
}

// masked-mean partials: grid (8 chunks, 32 b)
__global__ __launch_bounds__(256) void pool_partial_kernel(
    const float* __restrict__ subg, const float* __restrict__ incl,
    float* __restrict__ part, float* __restrict__ msump)
{
    int chunk = blockIdx.x, b = blockIdx.y, tid = threadIdx.x;
    float a0 = 0.f, a1 = 0.f, ms = 0.f;
    for (int l0 = 0; l0 < 128; ++l0) {
        int l = chunk * 128 + l0;
        float m = incl[b * LSEQ + l];
        const float* row = subg + ((size_t)b * LSEQ + l) * DMODEL;
        a0 += m * row[tid];
        a1 += m * row[tid + 256];
        ms += m;
    }
    int pi = (b * 8 + chunk) * DMODEL;
    part[pi + tid] = a0;
    part[pi + tid + 256] = a1;
    if (tid == 0) msump[b * 8 + chunk] = ms;
}

__global__ __launch_bounds__(256) void fc2_kernel(
    const float* __restrict__ part, const float* __restrict__ msump,
    const float* __restrict__ fc2w, const float* __restrict__ fc2b,
    float* __restrict__ out)
{
    int b = blockIdx.x, tid = threadIdx.x;
    __shared__ float pooled[DMODEL];
    float s0 = 0.f, s1 = 0.f, ms = 0.f;
#pragma unroll
    for (int c = 0; c < 8; ++c) {
        s0 += part[(b * 8 + c) * DMODEL + tid];
        s1 += part[(b * 8 + c) * DMODEL + tid + 256];
        ms += msump[b * 8 + c];
    }
    float inv = 1.f / (ms + 1e-5f);
    pooled[tid] = s0 * inv; pooled[tid + 256] = s1 * inv;
    __syncthreads();
    int wave = tid >> 6, lane = tid & 63;
    for (int c = wave; c < NCLASS; c += 4) {
        float s = 0.f;
#pragma unroll
        for (int k = lane; k < DMODEL; k += 64) s += pooled[k] * fc2w[c * DMODEL + k];
#pragma unroll
        for (int off = 32; off; off >>= 1) s += __shfl_xor(s, off, 64);
        if (lane == 0) out[b * NCLASS + c] = s + fc2b[c];
    }
}

// ---------------------------------------------------------------------------

extern "C" void kernel_launch(void* const* d_in, const int* in_sizes, int n_in,
                              void* d_out, int out_size, void* d_ws, size_t ws_size,
                              hipStream_t stream)
{
    (void)in_sizes; (void)n_in; (void)out_size; (void)ws_size;
    const int*   seq    = (const int*)  d_in[0];
    const float* incl   = (const float*)d_in[1];
    const float* emb    = (const float*)d_in[2];
    const float* fc1w   = (const float*)d_in[3];
    const float* fc1b   = (const float*)d_in[4];
    const float* fc2w   = (const float*)d_in[5];
    const float* fc2b   = (const float*)d_in[6];
    const float* nscale = (const float*)d_in[7];
    const float* ipw    = (const float*)d_in[8];
    const float* cw     = (const float*)d_in[9];
    const float* cbv    = (const float*)d_in[10];
    const float* xpw    = (const float*)d_in[11];
    const float* dtw    = (const float*)d_in[12];
    const float* dtb    = (const float*)d_in[13];
    const float* alog   = (const float*)d_in[14];
    const float* Dvec   = (const float*)d_in[15];
    const float* opw    = (const float*)d_in[16];
    float* outp = (float*)d_out;

    char* w = (char*)d_ws;
    size_t off = 0;
    auto take = [&](size_t bytes) {
        char* p = w + off; off += (bytes + 255) & ~(size_t)255; return p;
    };
    float* subg  = (float*)take((size_t)MROWS * DMODEL * 4);       // fp32 residual stream
    u16*   zi    = (u16*)  take((size_t)MROWS * DMODEL * 2);       // rmsnorm out
    u16*   xzb   = (u16*)  take((size_t)MROWS * 2 * DINNER * 2);   // in_proj out (xin|z)
    u16*   xconv = (u16*)  take((size_t)MROWS * DINNER * 2);       // conv+silu out
    u16*   xdbl  = (u16*)  take((size_t)MROWS * 128 * 2);          // x_proj out (pad 128)
    u16*   delta = (u16*)  take((size_t)MROWS * DINNER * 2);       // softplus(dt_proj)
    u16*   ybuf  = (u16*)  take((size_t)MROWS * DINNER * 2);       // scan out (gated)
    u16*   wip   = (u16*)  take((size_t)2 * 2 * DINNER * DMODEL * 2);
    u16*   wop   = (u16*)  take((size_t)2 * DMODEL * DINNER * 2);
    u16*   wxp   = (u16*)  take((size_t)2 * 128 * DINNER * 2);
    u16*   wdt   = (u16*)  take((size_t)2 * DINNER * DTRANK * 2);
    u16*   wfc1  = (u16*)  take((size_t)DMODEL * NFEAT * 2);
    float* part  = (float*)take((size_t)BATCH * 8 * DMODEL * 4);
    float* msump = (float*)take((size_t)BATCH * 8 * 4);
    u16*   gemb  = (u16*)delta;  // alias: gathered emb consumed before delta written

    // weight prep (ws re-poisoned every call, so redo each call)
    cvt_bf16_kernel<<<(DMODEL * NFEAT / 4 + 255) / 256, 256, 0, stream>>>(fc1w, wfc1, DMODEL * NFEAT / 4);
    cvt_bf16_kernel<<<(2 * 2 * DINNER * DMODEL / 4 + 255) / 256, 256, 0, stream>>>(ipw, wip, 2 * 2 * DINNER * DMODEL / 4);
    cvt_bf16_kernel<<<(2 * DMODEL * DINNER / 4 + 255) / 256, 256, 0, stream>>>(opw, wop, 2 * DMODEL * DINNER / 4);
    cvt_bf16_kernel<<<(2 * DINNER * DTRANK / 4 + 255) / 256, 256, 0, stream>>>(dtw, wdt, 2 * DINNER * DTRANK / 4);
    pad_xpw_kernel<<<(2 * 128 * DINNER / 4) / 256, 256, 0, stream>>>(xpw, wxp);
    gather_kernel<<<MROWS * (NFEAT / 4) / 256, 256, 0, stream>>>(seq, emb, gemb);

    // subg = gathered_emb @ fc1_w^T + fc1_b   (f32 out)
    gemm_bt<0, 0, 0><<<dim3(MROWS / 128, DMODEL / 128), 256, 0, stream>>>(
        gemb, NFEAT, wfc1, NFEAT, subg, DMODEL, fc1b, NFEAT);

    for (int i = 0; i < 2; ++i) {
        rmsnorm_kernel<<<MROWS / 4, 256, 0, stream>>>(subg, nscale + i * DMODEL, zi);
        // xz = zi @ in_proj_w^T  (bf16 out, N=2048)
        gemm_bt<1, 0, 0><<<dim3(MROWS / 128, 2 * DINNER / 128), 256, 0, stream>>>(
            zi, DMODEL, wip + (size_t)i * 2 * DINNER * DMODEL, DMODEL,
            xzb, 2 * DINNER, nullptr, DMODEL);
        conv_silu_kernel<<<MROWS * DINNER / 256, 256, 0, stream>>>(
            xzb, xzb, cw + i * DINNER * 4, cbv + i * DINNER, xconv);
        // x_dbl = xconv @ x_proj_w^T (N padded to 128)
        gemm_bt<1, 0, 0><<<dim3(MROWS / 128, 1), 256, 0, stream>>>(
            xconv, DINNER, wxp + (size_t)i * 128 * DINNER, DINNER,
            xdbl, 128, nullptr, DINNER);
        // delta = softplus(dt @ dt_proj_w^T + dt_proj_b)  (K=32)
        gemm_bt<1, 0, 1><<<dim3(MROWS / 128, DINNER / 128), 256, 0, stream>>>(
            xdbl, 128, wdt + (size_t)i * DINNER * DTRANK, DTRANK,
            delta, DINNER, dtb + i * DINNER, DTRANK);
        scan_kernel<<<(BATCH * DINNER * DSTATE) / 256, 256, 0, stream>>>(
            delta, xconv, xzb, xdbl, alog + i * DINNER * DSTATE, Dvec + i * DINNER, ybuf);
        // subg += y @ out_proj_w^T  (f32 accumulate)
        gemm_bt<0, 1, 0><<<dim3(MROWS / 128, DMODEL / 128), 256, 0, stream>>>(
            ybuf, DINNER, wop + (size_t)i * DMODEL * DINNER, DINNER,
            subg, DMODEL, nullptr, DINNER);
    }

    pool_partial_kernel<<<dim3(8, BATCH), 256, 0, stream>>>(subg, incl, part, msump);
    fc2_kernel<<<BATCH, 256, 0, stream>>>(part, msump, fc2w, fc2b, outp);
}

// Round 3
// 2029.808 us; speedup vs baseline: 1.9503x; 1.6274x over previous
//
#include <hip/hip_runtime.h>
#include <cstdint>
#include <cstddef>

#define LSEQ   1024
#define BATCH  32
#define NFEAT  512
#define DMODEL 512
#define DINNER 1024
#define DSTATE 16
#define DTRANK 32
#define NCLASS 40
#define MROWS  (BATCH * LSEQ)   // 32768
#define NCHUNK 16
#define CLEN   (LSEQ / NCHUNK)  // 64

typedef unsigned short u16;
typedef __attribute__((ext_vector_type(8))) __bf16 bf16x8;
typedef __attribute__((ext_vector_type(4))) float f32x4;
typedef __attribute__((ext_vector_type(8))) unsigned short u16x8;

__device__ __forceinline__ u16 f2bf(float x) {
    union { float f; unsigned u; } v; v.f = x;
    unsigned r = v.u + 0x7fffu + ((v.u >> 16) & 1u);   // round-to-nearest-even
    return (u16)(r >> 16);
}
__device__ __forceinline__ float bf2f(u16 h) {
    union { unsigned u; float f; } v; v.u = ((unsigned)h) << 16;
    return v.f;
}

#define GLL16(g, l) __builtin_amdgcn_global_load_lds( \
    (__attribute__((address_space(1))) void*)(g),     \
    (__attribute__((address_space(3))) void*)(l), 16, 0, 0)

// ---------------------------------------------------------------------------
// C[M,N] = A[M,K](bf16,lda) * B[N,K](bf16,ldb)^T  (+bias) (+softplus) ;
// OUT_BF16: store bf16; ACCUM: f32 +=. 128x128 tile, BK=32, 256 thr (4 waves).
// ---------------------------------------------------------------------------
template<int OUT_BF16, int ACCUM, int ACT>
__global__ __launch_bounds__(256) void gemm_bt(
    const u16* __restrict__ A, int lda,
    const u16* __restrict__ B, int ldb,
    void* __restrict__ Cv, int ldc,
    const float* __restrict__ bias, int K)
{
    __shared__ __align__(16) u16 As[128 * 32];
    __shared__ __align__(16) u16 Bs[128 * 32];
    const int tid  = threadIdx.x;
    const int m0   = blockIdx.x * 128;
    const int n0   = blockIdx.y * 128;
    const int r0   = tid >> 2;            // staging row (0..63), +64 for job 1
    const int c0   = (tid & 3) << 3;      // staging k-chunk (0,8,16,24)
    const int lane = tid & 63;
    const int wave = tid >> 6;
    const int wr   = (wave >> 1) << 6;    // wave row offset in tile
    const int wc   = (wave & 1) << 6;     // wave col offset in tile
    const int frow = lane & 15;
    const int fk   = (lane >> 4) << 3;
    const int quad = lane >> 4;

    const u16* Ap0 = A + (size_t)(m0 + r0) * lda + c0;
    const u16* Ap1 = Ap0 + (size_t)64 * lda;
    const u16* Bp0 = B + (size_t)(n0 + r0) * ldb + c0;
    const u16* Bp1 = Bp0 + (size_t)64 * ldb;
    u16* lA0 = As + tid * 8;  u16* lA1 = As + (tid + 256) * 8;
    u16* lB0 = Bs + tid * 8;  u16* lB1 = Bs + (tid + 256) * 8;

    f32x4 acc[4][4];
#pragma unroll
    for (int i = 0; i < 4; ++i)
#pragma unroll
        for (int j = 0; j < 4; ++j) acc[i][j] = (f32x4){0.f, 0.f, 0.f, 0.f};

    for (int k0 = 0; k0 < K; k0 += 32) {
        GLL16(Ap0 + k0, lA0);
        GLL16(Ap1 + k0, lA1);
        GLL16(Bp0 + k0, lB0);
        GLL16(Bp1 + k0, lB1);
        __syncthreads();
        bf16x8 af[4], bfr[4];
#pragma unroll
        for (int i = 0; i < 4; ++i) {
            af[i]  = *(const bf16x8*)(As + (wr + i * 16 + frow) * 32 + fk);
            bfr[i] = *(const bf16x8*)(Bs + (wc + i * 16 + frow) * 32 + fk);
        }
#pragma unroll
        for (int i = 0; i < 4; ++i)
#pragma unroll
            for (int j = 0; j < 4; ++j)
                acc[i][j] = __builtin_amdgcn_mfma_f32_16x16x32_bf16(
                    af[i], bfr[j], acc[i][j], 0, 0, 0);
        __syncthreads();
    }

    float bv[4];
#pragma unroll
    for (int j = 0; j < 4; ++j)
        bv[j] = bias ? bias[n0 + wc + j * 16 + frow] : 0.f;

#pragma unroll
    for (int i = 0; i < 4; ++i) {
#pragma unroll
        for (int r = 0; r < 4; ++r) {
            size_t row = (size_t)(m0 + wr + i * 16 + quad * 4 + r);
#pragma unroll
            for (int j = 0; j < 4; ++j) {
                size_t cidx = row * (size_t)ldc + (size_t)(n0 + wc + j * 16 + frow);
                float v = acc[i][j][r] + bv[j];
                if (ACT == 1) v = (v > 15.f) ? v : log1pf(expf(v));  // softplus
                if (OUT_BF16)      ((u16*)Cv)[cidx] = f2bf(v);
                else if (ACCUM)    ((float*)Cv)[cidx] += v;
                else               ((float*)Cv)[cidx] = v;
            }
        }
    }
}

// --------------------------- elementwise / prep ----------------------------

__global__ __launch_bounds__(256) void cvt_bf16_kernel(
    const float* __restrict__ src, u16* __restrict__ dst, int n4)
{
    int i = blockIdx.x * 256 + threadIdx.x;
    if (i >= n4) return;
    float4 v = ((const float4*)src)[i];
    ushort4 o; o.x = f2bf(v.x); o.y = f2bf(v.y); o.z = f2bf(v.z); o.w = f2bf(v.w);
    ((ushort4*)dst)[i] = o;
}

// x_proj_w (2,64,1024) f32 -> (2,128,1024) bf16, rows 64..127 zero
__global__ __launch_bounds__(256) void pad_xpw_kernel(
    const float* __restrict__ src, u16* __restrict__ dst)
{
    int i  = blockIdx.x * 256 + threadIdx.x;   // per float4; total 2*128*1024/4
    int k4 = i & 255;
    int r  = (i >> 8) & 127;
    int l  = i >> 15;
    ushort4 o;
    if (r < 64) {
        float4 v = ((const float4*)(src + ((size_t)l * 64 + r) * DINNER))[k4];
        o.x = f2bf(v.x); o.y = f2bf(v.y); o.z = f2bf(v.z); o.w = f2bf(v.w);
    } else { o.x = 0; o.y = 0; o.z = 0; o.w = 0; }
    ((ushort4*)dst)[i] = o;
}

// gathered_emb[m,:] = bf16(embeddings[sequence[m],:])
__global__ __launch_bounds__(256) void gather_kernel(
    const int* __restrict__ seq, const float* __restrict__ emb, u16* __restrict__ g)
{
    int i   = blockIdx.x * 256 + threadIdx.x;  // per float4; total MROWS*128
    int row = i >> 7, c = i & 127;
    int node = seq[row];
    float4 v = ((const float4*)(emb + (size_t)node * NFEAT))[c];
    ushort4 o; o.x = f2bf(v.x); o.y = f2bf(v.y); o.z = f2bf(v.z); o.w = f2bf(v.w);
    ((ushort4*)g)[i] = o;
}

// zi = scale * x / (||x||/sqrt(512) + 1e-8), one wave per row
__global__ __launch_bounds__(256) void rmsnorm_kernel(
    const float* __restrict__ x, const float* __restrict__ scale, u16* __restrict__ o)
{
    int wave = threadIdx.x >> 6, lane = threadIdx.x & 63;
    size_t row = (size_t)blockIdx.x * 4 + wave;
    const float4* xr = (const float4*)(x + row * DMODEL);
    float4 v0 = xr[lane], v1 = xr[lane + 64];
    float ss = v0.x*v0.x + v0.y*v0.y + v0.z*v0.z + v0.w*v0.w
             + v1.x*v1.x + v1.y*v1.y + v1.z*v1.z + v1.w*v1.w;
#pragma unroll
    for (int off = 32; off; off >>= 1) ss += __shfl_xor(ss, off, 64);
    float inv = 1.f / (sqrtf(ss * (1.f / DMODEL)) + 1e-8f);
    const float4* sc = (const float4*)scale;
    float4 s0 = sc[lane], s1 = sc[lane + 64];
    ushort4 o0, o1;
    o0.x = f2bf(v0.x * s0.x * inv); o0.y = f2bf(v0.y * s0.y * inv);
    o0.z = f2bf(v0.z * s0.z * inv); o0.w = f2bf(v0.w * s0.w * inv);
    o1.x = f2bf(v1.x * s1.x * inv); o1.y = f2bf(v1.y * s1.y * inv);
    o1.z = f2bf(v1.z * s1.z * inv); o1.w = f2bf(v1.w * s1.w * inv);
    ushort4* op = (ushort4*)(o + row * DMODEL);
    op[lane] = o0; op[lane + 64] = o1;
}

// causal depthwise conv (window 4) + bias + silu on x-half;
// ALSO: z-half of xz is replaced in-place by silu(z) (consumed only by scan).
__global__ __launch_bounds__(256) void conv_silu_kernel(
    const u16* __restrict__ xzc, u16* __restrict__ xzm,
    const float* __restrict__ w, const float* __restrict__ cbv,
    u16* __restrict__ xc)
{
    int idx = blockIdx.x * 256 + threadIdx.x;  // 0 .. MROWS*DINNER-1
    int d = idx & (DINNER - 1);
    int r = idx >> 10;                          // global row (b*L + l)
    int l = r & (LSEQ - 1);
    float acc = cbv[d];
    const float* wd = w + d * 4;
#pragma unroll
    for (int j = 0; j < 4; ++j) {
        int ls = l - 3 + j;
        if (ls >= 0) acc += wd[j] * bf2f(xzc[(size_t)(r - 3 + j) * (2 * DINNER) + d]);
    }
    float s = acc / (1.f + expf(-acc));         // silu
    xc[idx] = f2bf(s);
    // silu(z) in place
    size_t zi = (size_t)r * (2 * DINNER) + DINNER + d;
    float zv = bf2f(xzc[zi]);
    xzm[zi] = f2bf(zv / (1.f + expf(-zv)));
}

// ---------------------------------------------------------------------------
// Chunked selective scan. h_l = exp2(dt_l*a2_s)*h_{l-1} + dt_l*x_l*B_l[s].
// Chunk decay product = exp2(a2_s * sum(dt)) -> only scalar dtsum needed.
// p1: local scan per chunk (h0=0), store h_end[16] + dtsum.
// p2: carry recurrence across chunks; states <- exclusive incoming state.
// p3: re-run chunk seeded with incoming state; y = h.C; gate; write.
// Thread map p1/p3: t -> d = t&1023, k = (t>>10)&15, b = t>>14.
// states layout: [(b*16+k)*1024+d][16] f32 == states + t*16.
// ---------------------------------------------------------------------------
__global__ __launch_bounds__(256) void scan_p1(
    const u16* __restrict__ delta, const u16* __restrict__ xconv,
    const u16* __restrict__ xdbl, const float* __restrict__ alog,
    float* __restrict__ states, float* __restrict__ dtsums)
{
    int t = blockIdx.x * 256 + threadIdx.x;
    int d = t & (DINNER - 1);
    int k = (t >> 10) & (NCHUNK - 1);
    int b = t >> 14;

    float a2[DSTATE];
#pragma unroll
    for (int s = 0; s < DSTATE; ++s)
        a2[s] = -expf(alog[d * DSTATE + s]) * 1.44269504f;

    float h[DSTATE];
#pragma unroll
    for (int s = 0; s < DSTATE; ++s) h[s] = 0.f;
    float dtsum = 0.f;

    size_t r0 = (size_t)b * LSEQ + (size_t)k * CLEN;
    const u16* pd = delta + r0 * DINNER + d;
    const u16* px = xconv + r0 * DINNER + d;
    const u16* pB = xdbl + r0 * 128 + 32;

    for (int j = 0; j < CLEN; ++j) {
        float dt = bf2f(*pd);
        float xv = bf2f(*px);
        u16x8 q0 = *(const u16x8*)(pB);
        u16x8 q1 = *(const u16x8*)(pB + 8);
        float dx = dt * xv;
        dtsum += dt;
#pragma unroll
        for (int s = 0; s < 8; ++s)
            h[s] = h[s] * __builtin_amdgcn_exp2f(dt * a2[s]) + dx * bf2f(q0[s]);
#pragma unroll
        for (int s = 8; s < 16; ++s)
            h[s] = h[s] * __builtin_amdgcn_exp2f(dt * a2[s]) + dx * bf2f(q1[s - 8]);
        pd += DINNER; px += DINNER; pB += 128;
    }

    f32x4* st = (f32x4*)(states + (size_t)t * DSTATE);
#pragma unroll
    for (int q = 0; q < 4; ++q)
        st[q] = (f32x4){h[q * 4], h[q * 4 + 1], h[q * 4 + 2], h[q * 4 + 3]};
    dtsums[t] = dtsum;
}

__global__ __launch_bounds__(256) void scan_p2(
    float* __restrict__ states, const float* __restrict__ dtsums,
    const float* __restrict__ alog)
{
    int t = blockIdx.x * 256 + threadIdx.x;   // 0 .. B*DINNER*DSTATE-1
    int s = t & (DSTATE - 1);
    int d = (t >> 4) & (DINNER - 1);
    int b = t >> 14;
    float a2 = -expf(alog[d * DSTATE + s]) * 1.44269504f;
    float H = 0.f;
    for (int k = 0; k < NCHUNK; ++k) {
        size_t ci = ((size_t)b * NCHUNK + k) * DINNER + d;
        size_t idx = ci * DSTATE + s;
        float hk = states[idx];
        float P = __builtin_amdgcn_exp2f(a2 * dtsums[ci]);
        states[idx] = H;                 // exclusive incoming state for chunk k
        H = hk + P * H;
    }
}

__global__ __launch_bounds__(256) void scan_p3(
    const u16* __restrict__ delta, const u16* __restrict__ xconv,
    const u16* __restrict__ zsil, const u16* __restrict__ xdbl,
    const float* __restrict__ alog, const float* __restrict__ Dvec,
    const float* __restrict__ states, u16* __restrict__ ybuf)
{
    int t = blockIdx.x * 256 + threadIdx.x;
    int d = t & (DINNER - 1);
    int k = (t >> 10) & (NCHUNK - 1);
    int b = t >> 14;

    float a2[DSTATE];
#pragma unroll
    for (int s = 0; s < DSTATE; ++s)
        a2[s] = -expf(alog[d * DSTATE + s]) * 1.44269504f;
    float Dd = Dvec[d];

    float h[DSTATE];
    const f32x4* st = (const f32x4*)(states + (size_t)t * DSTATE);
#pragma unroll
    for (int q = 0; q < 4; ++q) {
        f32x4 v = st[q];
        h[q * 4] = v[0]; h[q * 4 + 1] = v[1]; h[q * 4 + 2] = v[2]; h[q * 4 + 3] = v[3];
    }

    size_t r0 = (size_t)b * LSEQ + (size_t)k * CLEN;
    const u16* pd = delta + r0 * DINNER + d;
    const u16* px = xconv + r0 * DINNER + d;
    const u16* pz = zsil + r0 * (2 * DINNER) + DINNER + d;
    const u16* pB = xdbl + r0 * 128 + 32;
    u16* py = ybuf + r0 * DINNER + d;

    for (int j = 0; j < CLEN; ++j) {
        float dt = bf2f(*pd);
        float xv = bf2f(*px);
        u16x8 q0 = *(const u16x8*)(pB);        // Bm[0..7]
        u16x8 q1 = *(const u16x8*)(pB + 8);    // Bm[8..15]
        u16x8 q2 = *(const u16x8*)(pB + 16);   // Cm[0..7]
        u16x8 q3 = *(const u16x8*)(pB + 24);   // Cm[8..15]
        float dx = dt * xv;
        float yv = 0.f;
#pragma unroll
        for (int s = 0; s < 8; ++s) {
            h[s] = h[s] * __builtin_amdgcn_exp2f(dt * a2[s]) + dx * bf2f(q0[s]);
            yv += h[s] * bf2f(q2[s]);
        }
#pragma unroll
        for (int s = 8; s < 16; ++s) {
            h[s] = h[s] * __builtin_amdgcn_exp2f(dt * a2[s]) + dx * bf2f(q1[s - 8]);
            yv += h[s] * bf2f(q3[s - 8]);
        }
        float zs = bf2f(*pz);
        *py = f2bf((yv + Dd * xv) * zs);
        pd += DINNER; px += DINNER; pz += 2 * DINNER; pB += 128; py += DINNER;
    }
}

// masked-mean partials: grid (8 chunks, 32 b)
__global__ __launch_bounds__(256) void pool_partial_kernel(
    const float* __restrict__ subg, const float* __restrict__ incl,
    float* __restrict__ part, float* __restrict__ msump)
{
    int chunk = blockIdx.x, b = blockIdx.y, tid = threadIdx.x;
    float a0 = 0.f, a1 = 0.f, ms = 0.f;
    for (int l0 = 0; l0 < 128; ++l0) {
        int l = chunk * 128 + l0;
        float m = incl[b * LSEQ + l];
        const float* row = subg + ((size_t)b * LSEQ + l) * DMODEL;
        a0 += m * row[tid];
        a1 += m * row[tid + 256];
        ms += m;
    }
    int pi = (b * 8 + chunk) * DMODEL;
    part[pi + tid] = a0;
    part[pi + tid + 256] = a1;
    if (tid == 0) msump[b * 8 + chunk] = ms;
}

__global__ __launch_bounds__(256) void fc2_kernel(
    const float* __restrict__ part, const float* __restrict__ msump,
    const float* __restrict__ fc2w, const float* __restrict__ fc2b,
    float* __restrict__ out)
{
    int b = blockIdx.x, tid = threadIdx.x;
    __shared__ float pooled[DMODEL];
    float s0 = 0.f, s1 = 0.f, ms = 0.f;
#pragma unroll
    for (int c = 0; c < 8; ++c) {
        s0 += part[(b * 8 + c) * DMODEL + tid];
        s1 += part[(b * 8 + c) * DMODEL + tid + 256];
        ms += msump[b * 8 + c];
    }
    float inv = 1.f / (ms + 1e-5f);
    pooled[tid] = s0 * inv; pooled[tid + 256] = s1 * inv;
    __syncthreads();
    int wave = tid >> 6, lane = tid & 63;
    for (int c = wave; c < NCLASS; c += 4) {
        float s = 0.f;
#pragma unroll
        for (int k = lane; k < DMODEL; k += 64) s += pooled[k] * fc2w[c * DMODEL + k];
#pragma unroll
        for (int off = 32; off; off >>= 1) s += __shfl_xor(s, off, 64);
        if (lane == 0) out[b * NCLASS + c] = s + fc2b[c];
    }
}

// ---------------------------------------------------------------------------

extern "C" void kernel_launch(void* const* d_in, const int* in_sizes, int n_in,
                              void* d_out, int out_size, void* d_ws, size_t ws_size,
                              hipStream_t stream)
{
    (void)in_sizes; (void)n_in; (void)out_size; (void)ws_size;
    const int*   seq    = (const int*)  d_in[0];
    const float* incl   = (const float*)d_in[1];
    const float* emb    = (const float*)d_in[2];
    const float* fc1w   = (const float*)d_in[3];
    const float* fc1b   = (const float*)d_in[4];
    const float* fc2w   = (const float*)d_in[5];
    const float* fc2b   = (const float*)d_in[6];
    const float* nscale = (const float*)d_in[7];
    const float* ipw    = (const float*)d_in[8];
    const float* cw     = (const float*)d_in[9];
    const float* cbv    = (const float*)d_in[10];
    const float* xpw    = (const float*)d_in[11];
    const float* dtw    = (const float*)d_in[12];
    const float* dtb    = (const float*)d_in[13];
    const float* alog   = (const float*)d_in[14];
    const float* Dvec   = (const float*)d_in[15];
    const float* opw    = (const float*)d_in[16];
    float* outp = (float*)d_out;

    char* w = (char*)d_ws;
    size_t off = 0;
    auto take = [&](size_t bytes) {
        char* p = w + off; off += (bytes + 255) & ~(size_t)255; return p;
    };
    float* subg  = (float*)take((size_t)MROWS * DMODEL * 4);       // fp32 residual stream
    u16*   zi    = (u16*)  take((size_t)MROWS * DMODEL * 2);       // rmsnorm out (33.5MB)
    u16*   xzb   = (u16*)  take((size_t)MROWS * 2 * DINNER * 2);   // in_proj out (xin|z)
    u16*   xconv = (u16*)  take((size_t)MROWS * DINNER * 2);       // conv+silu out
    u16*   xdbl  = (u16*)  take((size_t)MROWS * 128 * 2);          // x_proj out (pad 128)
    u16*   delta = (u16*)  take((size_t)MROWS * DINNER * 2);       // softplus(dt_proj)
    u16*   ybuf  = (u16*)  take((size_t)MROWS * DINNER * 2);       // scan out (gated)
    u16*   wip   = (u16*)  take((size_t)2 * 2 * DINNER * DMODEL * 2);
    u16*   wop   = (u16*)  take((size_t)2 * DMODEL * DINNER * 2);
    u16*   wxp   = (u16*)  take((size_t)2 * 128 * DINNER * 2);
    u16*   wdt   = (u16*)  take((size_t)2 * DINNER * DTRANK * 2);
    u16*   wfc1  = (u16*)  take((size_t)DMODEL * NFEAT * 2);
    float* part  = (float*)take((size_t)BATCH * 8 * DMODEL * 4);
    float* msump = (float*)take((size_t)BATCH * 8 * 4);
    float* dtsums= (float*)take((size_t)BATCH * NCHUNK * DINNER * 4);  // 2 MB
    u16*   gemb  = (u16*)delta;   // alias: gathered emb consumed before delta written
    float* states= (float*)zi;    // alias: zi dead after in_proj GEMM each layer (same 33.5MB)

    // weight prep (ws re-poisoned every call, so redo each call)
    cvt_bf16_kernel<<<(DMODEL * NFEAT / 4 + 255) / 256, 256, 0, stream>>>(fc1w, wfc1, DMODEL * NFEAT / 4);
    cvt_bf16_kernel<<<(2 * 2 * DINNER * DMODEL / 4 + 255) / 256, 256, 0, stream>>>(ipw, wip, 2 * 2 * DINNER * DMODEL / 4);
    cvt_bf16_kernel<<<(2 * DMODEL * DINNER / 4 + 255) / 256, 256, 0, stream>>>(opw, wop, 2 * DMODEL * DINNER / 4);
    cvt_bf16_kernel<<<(2 * DINNER * DTRANK / 4 + 255) / 256, 256, 0, stream>>>(dtw, wdt, 2 * DINNER * DTRANK / 4);
    pad_xpw_kernel<<<(2 * 128 * DINNER / 4) / 256, 256, 0, stream>>>(xpw, wxp);
    gather_kernel<<<MROWS * (NFEAT / 4) / 256, 256, 0, stream>>>(seq, emb, gemb);

    // subg = gathered_emb @ fc1_w^T + fc1_b   (f32 out)
    gemm_bt<0, 0, 0><<<dim3(MROWS / 128, DMODEL / 128), 256, 0, stream>>>(
        gemb, NFEAT, wfc1, NFEAT, subg, DMODEL, fc1b, NFEAT);

    const int scan_blocks = (BATCH * NCHUNK * DINNER) / 256;   // 2048
    for (int i = 0; i < 2; ++i) {
        const float* al = alog + i * DINNER * DSTATE;
        rmsnorm_kernel<<<MROWS / 4, 256, 0, stream>>>(subg, nscale + i * DMODEL, zi);
        // xz = zi @ in_proj_w^T  (bf16 out, N=2048)
        gemm_bt<1, 0, 0><<<dim3(MROWS / 128, 2 * DINNER / 128), 256, 0, stream>>>(
            zi, DMODEL, wip + (size_t)i * 2 * DINNER * DMODEL, DMODEL,
            xzb, 2 * DINNER, nullptr, DMODEL);
        conv_silu_kernel<<<MROWS * DINNER / 256, 256, 0, stream>>>(
            xzb, xzb, cw + i * DINNER * 4, cbv + i * DINNER, xconv);
        // x_dbl = xconv @ x_proj_w^T (N padded to 128)
        gemm_bt<1, 0, 0><<<dim3(MROWS / 128, 1), 256, 0, stream>>>(
            xconv, DINNER, wxp + (size_t)i * 128 * DINNER, DINNER,
            xdbl, 128, nullptr, DINNER);
        // delta = softplus(dt @ dt_proj_w^T + dt_proj_b)  (K=32)
        gemm_bt<1, 0, 1><<<dim3(MROWS / 128, DINNER / 128), 256, 0, stream>>>(
            xdbl, 128, wdt + (size_t)i * DINNER * DTRANK, DTRANK,
            delta, DINNER, dtb + i * DINNER, DTRANK);
        // chunked scan
        scan_p1<<<scan_blocks, 256, 0, stream>>>(delta, xconv, xdbl, al, states, dtsums);
        scan_p2<<<scan_blocks, 256, 0, stream>>>(states, dtsums, al);
        scan_p3<<<scan_blocks, 256, 0, stream>>>(delta, xconv, xzb, xdbl, al,
                                                 Dvec + i * DINNER, states, ybuf);
        // subg += y @ out_proj_w^T  (f32 accumulate)
        gemm_bt<0, 1, 0><<<dim3(MROWS / 128, DMODEL / 128), 256, 0, stream>>>(
            ybuf, DINNER, wop + (size_t)i * DMODEL * DINNER, DINNER,
            subg, DMODEL, nullptr, DINNER);
    }

    pool_partial_kernel<<<dim3(8, BATCH), 256, 0, stream>>>(subg, incl, part, msump);
    fc2_kernel<<<BATCH, 256, 0, stream>>>(part, msump, fc2w, fc2b, outp);
}

// Round 4
// 1921.012 us; speedup vs baseline: 2.0608x; 1.0566x over previous
//
#include <hip/hip_runtime.h>
#include <cstdint>
#include <cstddef>

#define LSEQ   1024
#define BATCH  32
#define NFEAT  512
#define DMODEL 512
#define DINNER 1024
#define DSTATE 16
#define DTRANK 32
#define NCLASS 40
#define MROWS  (BATCH * LSEQ)   // 32768
#define NCHUNK 16
#define CLEN   (LSEQ / NCHUNK)  // 64

typedef unsigned short u16;
typedef __attribute__((ext_vector_type(8))) __bf16 bf16x8;
typedef __attribute__((ext_vector_type(4))) float f32x4;
typedef __attribute__((ext_vector_type(8))) unsigned short u16x8;

__device__ __forceinline__ u16 f2bf(float x) {
    union { float f; unsigned u; } v; v.f = x;
    unsigned r = v.u + 0x7fffu + ((v.u >> 16) & 1u);   // round-to-nearest-even
    return (u16)(r >> 16);
}
__device__ __forceinline__ float bf2f(u16 h) {
    union { unsigned u; float f; } v; v.u = ((unsigned)h) << 16;
    return v.f;
}

// dA[s] = g^(s+1), s=0..15, via 4-deep multiply tree (18 muls, no trans).
__device__ __forceinline__ void pow_dA(float g, float* dA) {
    float p2 = g * g, p4 = p2 * p2, p8 = p4 * p4;
    dA[0] = g;        dA[1] = p2;       dA[2] = p2 * g;   dA[3] = p4;
    dA[4] = p4 * g;   dA[5] = p4 * p2;  dA[6] = p4 * dA[2]; dA[7] = p8;
    dA[8] = p8 * g;   dA[9] = p8 * p2;  dA[10] = p8 * dA[2]; dA[11] = p8 * p4;
    dA[12] = p8 * dA[4]; dA[13] = p8 * dA[5]; dA[14] = p8 * dA[6]; dA[15] = p8 * p8;
}

#define GLL16(g, l) __builtin_amdgcn_global_load_lds( \
    (__attribute__((address_space(1))) void*)(g),     \
    (__attribute__((address_space(3))) void*)(l), 16, 0, 0)

// ---------------------------------------------------------------------------
// C[M,N] = A[M,K](bf16,lda) * B[N,K](bf16,ldb)^T  (+bias) (+softplus) ;
// OUT_BF16: store bf16; ACCUM: f32 +=. 128x128 tile, BK=32, 256 thr (4 waves).
// ---------------------------------------------------------------------------
template<int OUT_BF16, int ACCUM, int ACT>
__global__ __launch_bounds__(256) void gemm_bt(
    const u16* __restrict__ A, int lda,
    const u16* __restrict__ B, int ldb,
    void* __restrict__ Cv, int ldc,
    const float* __restrict__ bias, int K)
{
    __shared__ __align__(16) u16 As[128 * 32];
    __shared__ __align__(16) u16 Bs[128 * 32];
    const int tid  = threadIdx.x;
    const int m0   = blockIdx.x * 128;
    const int n0   = blockIdx.y * 128;
    const int r0   = tid >> 2;            // staging row (0..63), +64 for job 1
    const int c0   = (tid & 3) << 3;      // staging k-chunk (0,8,16,24)
    const int lane = tid & 63;
    const int wave = tid >> 6;
    const int wr   = (wave >> 1) << 6;    // wave row offset in tile
    const int wc   = (wave & 1) << 6;     // wave col offset in tile
    const int frow = lane & 15;
    const int fk   = (lane >> 4) << 3;
    const int quad = lane >> 4;

    const u16* Ap0 = A + (size_t)(m0 + r0) * lda + c0;
    const u16* Ap1 = Ap0 + (size_t)64 * lda;
    const u16* Bp0 = B + (size_t)(n0 + r0) * ldb + c0;
    const u16* Bp1 = Bp0 + (size_t)64 * ldb;
    u16* lA0 = As + tid * 8;  u16* lA1 = As + (tid + 256) * 8;
    u16* lB0 = Bs + tid * 8;  u16* lB1 = Bs + (tid + 256) * 8;

    f32x4 acc[4][4];
#pragma unroll
    for (int i = 0; i < 4; ++i)
#pragma unroll
        for (int j = 0; j < 4; ++j) acc[i][j] = (f32x4){0.f, 0.f, 0.f, 0.f};

    for (int k0 = 0; k0 < K; k0 += 32) {
        GLL16(Ap0 + k0, lA0);
        GLL16(Ap1 + k0, lA1);
        GLL16(Bp0 + k0, lB0);
        GLL16(Bp1 + k0, lB1);
        __syncthreads();
        bf16x8 af[4], bfr[4];
#pragma unroll
        for (int i = 0; i < 4; ++i) {
            af[i]  = *(const bf16x8*)(As + (wr + i * 16 + frow) * 32 + fk);
            bfr[i] = *(const bf16x8*)(Bs + (wc + i * 16 + frow) * 32 + fk);
        }
#pragma unroll
        for (int i = 0; i < 4; ++i)
#pragma unroll
            for (int j = 0; j < 4; ++j)
                acc[i][j] = __builtin_amdgcn_mfma_f32_16x16x32_bf16(
                    af[i], bfr[j], acc[i][j], 0, 0, 0);
        __syncthreads();
    }

    float bv[4];
#pragma unroll
    for (int j = 0; j < 4; ++j)
        bv[j] = bias ? bias[n0 + wc + j * 16 + frow] : 0.f;

#pragma unroll
    for (int i = 0; i < 4; ++i) {
#pragma unroll
        for (int r = 0; r < 4; ++r) {
            size_t row = (size_t)(m0 + wr + i * 16 + quad * 4 + r);
#pragma unroll
            for (int j = 0; j < 4; ++j) {
                size_t cidx = row * (size_t)ldc + (size_t)(n0 + wc + j * 16 + frow);
                float v = acc[i][j][r] + bv[j];
                if (ACT == 1) v = (v > 15.f) ? v : log1pf(expf(v));  // softplus
                if (OUT_BF16)      ((u16*)Cv)[cidx] = f2bf(v);
                else if (ACCUM)    ((float*)Cv)[cidx] += v;
                else               ((float*)Cv)[cidx] = v;
            }
        }
    }
}

// --------------------------- elementwise / prep ----------------------------

__global__ __launch_bounds__(256) void cvt_bf16_kernel(
    const float* __restrict__ src, u16* __restrict__ dst, int n4)
{
    int i = blockIdx.x * 256 + threadIdx.x;
    if (i >= n4) return;
    float4 v = ((const float4*)src)[i];
    ushort4 o; o.x = f2bf(v.x); o.y = f2bf(v.y); o.z = f2bf(v.z); o.w = f2bf(v.w);
    ((ushort4*)dst)[i] = o;
}

// x_proj_w (2,64,1024) f32 -> (2,128,1024) bf16, rows 64..127 zero
__global__ __launch_bounds__(256) void pad_xpw_kernel(
    const float* __restrict__ src, u16* __restrict__ dst)
{
    int i  = blockIdx.x * 256 + threadIdx.x;   // per float4; total 2*128*1024/4
    int k4 = i & 255;
    int r  = (i >> 8) & 127;
    int l  = i >> 15;
    ushort4 o;
    if (r < 64) {
        float4 v = ((const float4*)(src + ((size_t)l * 64 + r) * DINNER))[k4];
        o.x = f2bf(v.x); o.y = f2bf(v.y); o.z = f2bf(v.z); o.w = f2bf(v.w);
    } else { o.x = 0; o.y = 0; o.z = 0; o.w = 0; }
    ((ushort4*)dst)[i] = o;
}

// gathered_emb[m,:] = bf16(embeddings[sequence[m],:])
__global__ __launch_bounds__(256) void gather_kernel(
    const int* __restrict__ seq, const float* __restrict__ emb, u16* __restrict__ g)
{
    int i   = blockIdx.x * 256 + threadIdx.x;  // per float4; total MROWS*128
    int row = i >> 7, c = i & 127;
    int node = seq[row];
    float4 v = ((const float4*)(emb + (size_t)node * NFEAT))[c];
    ushort4 o; o.x = f2bf(v.x); o.y = f2bf(v.y); o.z = f2bf(v.z); o.w = f2bf(v.w);
    ((ushort4*)g)[i] = o;
}

// zi = scale * x / (||x||/sqrt(512) + 1e-8), one wave per row
__global__ __launch_bounds__(256) void rmsnorm_kernel(
    const float* __restrict__ x, const float* __restrict__ scale, u16* __restrict__ o)
{
    int wave = threadIdx.x >> 6, lane = threadIdx.x & 63;
    size_t row = (size_t)blockIdx.x * 4 + wave;
    const float4* xr = (const float4*)(x + row * DMODEL);
    float4 v0 = xr[lane], v1 = xr[lane + 64];
    float ss = v0.x*v0.x + v0.y*v0.y + v0.z*v0.z + v0.w*v0.w
             + v1.x*v1.x + v1.y*v1.y + v1.z*v1.z + v1.w*v1.w;
#pragma unroll
    for (int off = 32; off; off >>= 1) ss += __shfl_xor(ss, off, 64);
    float inv = 1.f / (sqrtf(ss * (1.f / DMODEL)) + 1e-8f);
    const float4* sc = (const float4*)scale;
    float4 s0 = sc[lane], s1 = sc[lane + 64];
    ushort4 o0, o1;
    o0.x = f2bf(v0.x * s0.x * inv); o0.y = f2bf(v0.y * s0.y * inv);
    o0.z = f2bf(v0.z * s0.z * inv); o0.w = f2bf(v0.w * s0.w * inv);
    o1.x = f2bf(v1.x * s1.x * inv); o1.y = f2bf(v1.y * s1.y * inv);
    o1.z = f2bf(v1.z * s1.z * inv); o1.w = f2bf(v1.w * s1.w * inv);
    ushort4* op = (ushort4*)(o + row * DMODEL);
    op[lane] = o0; op[lane + 64] = o1;
}

// causal depthwise conv (window 4) + bias + silu on x-half; 8 channels/thread,
// u16x8 vector loads. z-half replaced in-place by silu(z).
__global__ __launch_bounds__(256) void conv_silu_kernel(
    const u16* __restrict__ xz, u16* __restrict__ xzm,
    const float* __restrict__ w, const float* __restrict__ cbv,
    u16* __restrict__ xc)
{
    int i  = blockIdx.x * 256 + threadIdx.x;   // MROWS*128 total
    int d0 = (i & 127) << 3;
    int r  = i >> 7;
    int l  = r & (LSEQ - 1);
    const u16* bx = xz + (size_t)r * (2 * DINNER) + d0;
    u16x8 zero{};
    u16x8 t3 = *(const u16x8*)(bx);
    u16x8 t2 = (l >= 1) ? *(const u16x8*)(bx - 2 * DINNER) : zero;
    u16x8 t1 = (l >= 2) ? *(const u16x8*)(bx - 4 * DINNER) : zero;
    u16x8 t0 = (l >= 3) ? *(const u16x8*)(bx - 6 * DINNER) : zero;
    u16x8 zl = *(const u16x8*)(bx + DINNER);
    u16x8 oc, oz;
#pragma unroll
    for (int c = 0; c < 8; ++c) {
        float4 wc = ((const float4*)w)[d0 + c];
        float acc = cbv[d0 + c]
                  + wc.x * bf2f(t0[c]) + wc.y * bf2f(t1[c])
                  + wc.z * bf2f(t2[c]) + wc.w * bf2f(t3[c]);
        oc[c] = f2bf(acc / (1.f + expf(-acc)));
        float zv = bf2f(zl[c]);
        oz[c] = f2bf(zv / (1.f + expf(-zv)));
    }
    *(u16x8*)(xc + (size_t)r * DINNER + d0) = oc;
    *(u16x8*)(xzm + (size_t)r * (2 * DINNER) + DINNER + d0) = oz;
}

// ---------------------------------------------------------------------------
// Chunked selective scan. h_l = exp2(dt_l*a2_s)*h_{l-1} + dt_l*x_l*B_l[s].
// S4D structure fast path: a2[s] = (s+1)*a2[0]  ->  dA[s] = g^(s+1),
// g = exp2(dt*a2[0]): 1 trans + 18 muls instead of 16 trans + 16 muls.
// Detected per-thread at init; generic fallback kept for correctness.
// ---------------------------------------------------------------------------
__device__ __forceinline__ int detect_s4d(const float* a2) {
    int fast = 1;
#pragma unroll
    for (int s = 1; s < DSTATE; ++s)
        fast &= (__builtin_fabsf(a2[s] - (float)(s + 1) * a2[0]) <=
                 1e-4f * (float)(s + 1) * __builtin_fabsf(a2[0]) + 1e-6f);
    return fast;
}

__global__ __launch_bounds__(256) void scan_p1(
    const u16* __restrict__ delta, const u16* __restrict__ xconv,
    const u16* __restrict__ xdbl, const float* __restrict__ alog,
    float* __restrict__ states, float* __restrict__ dtsums)
{
    int t = blockIdx.x * 256 + threadIdx.x;
    int d = t & (DINNER - 1);
    int k = (t >> 10) & (NCHUNK - 1);
    int b = t >> 14;

    float a2[DSTATE];
#pragma unroll
    for (int s = 0; s < DSTATE; ++s)
        a2[s] = -expf(alog[d * DSTATE + s]) * 1.44269504f;
    int fastA = detect_s4d(a2);
    float ab = a2[0];

    float h[DSTATE];
#pragma unroll
    for (int s = 0; s < DSTATE; ++s) h[s] = 0.f;
    float dtsum = 0.f;

    size_t r0 = (size_t)b * LSEQ + (size_t)k * CLEN;
    const u16* pd = delta + r0 * DINNER + d;
    const u16* px = xconv + r0 * DINNER + d;
    const u16* pB = xdbl + r0 * 128 + 32;

    if (fastA) {
        for (int j = 0; j < CLEN; ++j) {
            float dt = bf2f(*pd);
            float xv = bf2f(*px);
            u16x8 q0 = *(const u16x8*)(pB);
            u16x8 q1 = *(const u16x8*)(pB + 8);
            float dx = dt * xv;
            dtsum += dt;
            float dA[DSTATE];
            pow_dA(__builtin_amdgcn_exp2f(dt * ab), dA);
#pragma unroll
            for (int s = 0; s < 8; ++s)
                h[s] = h[s] * dA[s] + dx * bf2f(q0[s]);
#pragma unroll
            for (int s = 8; s < 16; ++s)
                h[s] = h[s] * dA[s] + dx * bf2f(q1[s - 8]);
            pd += DINNER; px += DINNER; pB += 128;
        }
    } else {
        for (int j = 0; j < CLEN; ++j) {
            float dt = bf2f(*pd);
            float xv = bf2f(*px);
            u16x8 q0 = *(const u16x8*)(pB);
            u16x8 q1 = *(const u16x8*)(pB + 8);
            float dx = dt * xv;
            dtsum += dt;
#pragma unroll
            for (int s = 0; s < 8; ++s)
                h[s] = h[s] * __builtin_amdgcn_exp2f(dt * a2[s]) + dx * bf2f(q0[s]);
#pragma unroll
            for (int s = 8; s < 16; ++s)
                h[s] = h[s] * __builtin_amdgcn_exp2f(dt * a2[s]) + dx * bf2f(q1[s - 8]);
            pd += DINNER; px += DINNER; pB += 128;
        }
    }

    f32x4* st = (f32x4*)(states + (size_t)t * DSTATE);
#pragma unroll
    for (int q = 0; q < 4; ++q)
        st[q] = (f32x4){h[q * 4], h[q * 4 + 1], h[q * 4 + 2], h[q * 4 + 3]};
    dtsums[t] = dtsum;
}

__global__ __launch_bounds__(256) void scan_p2(
    float* __restrict__ states, const float* __restrict__ dtsums,
    const float* __restrict__ alog)
{
    int t = blockIdx.x * 256 + threadIdx.x;   // 0 .. B*DINNER*DSTATE-1
    int s = t & (DSTATE - 1);
    int d = (t >> 4) & (DINNER - 1);
    int b = t >> 14;
    float a2 = -expf(alog[d * DSTATE + s]) * 1.44269504f;
    float H = 0.f;
    for (int k = 0; k < NCHUNK; ++k) {
        size_t ci = ((size_t)b * NCHUNK + k) * DINNER + d;
        size_t idx = ci * DSTATE + s;
        float hk = states[idx];
        float P = __builtin_amdgcn_exp2f(a2 * dtsums[ci]);
        states[idx] = H;                 // exclusive incoming state for chunk k
        H = hk + P * H;
    }
}

__global__ __launch_bounds__(256) void scan_p3(
    const u16* __restrict__ delta, const u16* __restrict__ xconv,
    const u16* __restrict__ zsil, const u16* __restrict__ xdbl,
    const float* __restrict__ alog, const float* __restrict__ Dvec,
    const float* __restrict__ states, u16* __restrict__ ybuf)
{
    int t = blockIdx.x * 256 + threadIdx.x;
    int d = t & (DINNER - 1);
    int k = (t >> 10) & (NCHUNK - 1);
    int b = t >> 14;

    float a2[DSTATE];
#pragma unroll
    for (int s = 0; s < DSTATE; ++s)
        a2[s] = -expf(alog[d * DSTATE + s]) * 1.44269504f;
    int fastA = detect_s4d(a2);
    float ab = a2[0];
    float Dd = Dvec[d];

    float h[DSTATE];
    const f32x4* st = (const f32x4*)(states + (size_t)t * DSTATE);
#pragma unroll
    for (int q = 0; q < 4; ++q) {
        f32x4 v = st[q];
        h[q * 4] = v[0]; h[q * 4 + 1] = v[1]; h[q * 4 + 2] = v[2]; h[q * 4 + 3] = v[3];
    }

    size_t r0 = (size_t)b * LSEQ + (size_t)k * CLEN;
    const u16* pd = delta + r0 * DINNER + d;
    const u16* px = xconv + r0 * DINNER + d;
    const u16* pz = zsil + r0 * (2 * DINNER) + DINNER + d;
    const u16* pB = xdbl + r0 * 128 + 32;
    u16* py = ybuf + r0 * DINNER + d;

    if (fastA) {
        for (int j = 0; j < CLEN; ++j) {
            float dt = bf2f(*pd);
            float xv = bf2f(*px);
            u16x8 q0 = *(const u16x8*)(pB);        // Bm[0..7]
            u16x8 q1 = *(const u16x8*)(pB + 8);    // Bm[8..15]
            u16x8 q2 = *(const u16x8*)(pB + 16);   // Cm[0..7]
            u16x8 q3 = *(const u16x8*)(pB + 24);   // Cm[8..15]
            float dx = dt * xv;
            float yv = 0.f;
            float dA[DSTATE];
            pow_dA(__builtin_amdgcn_exp2f(dt * ab), dA);
#pragma unroll
            for (int s = 0; s < 8; ++s) {
                h[s] = h[s] * dA[s] + dx * bf2f(q0[s]);
                yv += h[s] * bf2f(q2[s]);
            }
#pragma unroll
            for (int s = 8; s < 16; ++s) {
                h[s] = h[s] * dA[s] + dx * bf2f(q1[s - 8]);
                yv += h[s] * bf2f(q3[s - 8]);
            }
            float zs = bf2f(*pz);
            *py = f2bf((yv + Dd * xv) * zs);
            pd += DINNER; px += DINNER; pz += 2 * DINNER; pB += 128; py += DINNER;
        }
    } else {
        for (int j = 0; j < CLEN; ++j) {
            float dt = bf2f(*pd);
            float xv = bf2f(*px);
            u16x8 q0 = *(const u16x8*)(pB);
            u16x8 q1 = *(const u16x8*)(pB + 8);
            u16x8 q2 = *(const u16x8*)(pB + 16);
            u16x8 q3 = *(const u16x8*)(pB + 24);
            float dx = dt * xv;
            float yv = 0.f;
#pragma unroll
            for (int s = 0; s < 8; ++s) {
                h[s] = h[s] * __builtin_amdgcn_exp2f(dt * a2[s]) + dx * bf2f(q0[s]);
                yv += h[s] * bf2f(q2[s]);
            }
#pragma unroll
            for (int s = 8; s < 16; ++s) {
                h[s] = h[s] * __builtin_amdgcn_exp2f(dt * a2[s]) + dx * bf2f(q1[s - 8]);
                yv += h[s] * bf2f(q3[s - 8]);
            }
            float zs = bf2f(*pz);
            *py = f2bf((yv + Dd * xv) * zs);
            pd += DINNER; px += DINNER; pz += 2 * DINNER; pB += 128; py += DINNER;
        }
    }
}

// masked-mean partials: grid (8 chunks, 32 b)
__global__ __launch_bounds__(256) void pool_partial_kernel(
    const float* __restrict__ subg, const float* __restrict__ incl,
    float* __restrict__ part, float* __restrict__ msump)
{
    int chunk = blockIdx.x, b = blockIdx.y, tid = threadIdx.x;
    float a0 = 0.f, a1 = 0.f, ms = 0.f;
    for (int l0 = 0; l0 < 128; ++l0) {
        int l = chunk * 128 + l0;
        float m = incl[b * LSEQ + l];
        const float* row = subg + ((size_t)b * LSEQ + l) * DMODEL;
        a0 += m * row[tid];
        a1 += m * row[tid + 256];
        ms += m;
    }
    int pi = (b * 8 + chunk) * DMODEL;
    part[pi + tid] = a0;
    part[pi + tid + 256] = a1;
    if (tid == 0) msump[b * 8 + chunk] = ms;
}

__global__ __launch_bounds__(256) void fc2_kernel(
    const float* __restrict__ part, const float* __restrict__ msump,
    const float* __restrict__ fc2w, const float* __restrict__ fc2b,
    float* __restrict__ out)
{
    int b = blockIdx.x, tid = threadIdx.x;
    __shared__ float pooled[DMODEL];
    float s0 = 0.f, s1 = 0.f, ms = 0.f;
#pragma unroll
    for (int c = 0; c < 8; ++c) {
        s0 += part[(b * 8 + c) * DMODEL + tid];
        s1 += part[(b * 8 + c) * DMODEL + tid + 256];
        ms += msump[b * 8 + c];
    }
    float inv = 1.f / (ms + 1e-5f);
    pooled[tid] = s0 * inv; pooled[tid + 256] = s1 * inv;
    __syncthreads();
    int wave = tid >> 6, lane = tid & 63;
    for (int c = wave; c < NCLASS; c += 4) {
        float s = 0.f;
#pragma unroll
        for (int k = lane; k < DMODEL; k += 64) s += pooled[k] * fc2w[c * DMODEL + k];
#pragma unroll
        for (int off = 32; off; off >>= 1) s += __shfl_xor(s, off, 64);
        if (lane == 0) out[b * NCLASS + c] = s + fc2b[c];
    }
}

// ---------------------------------------------------------------------------

extern "C" void kernel_launch(void* const* d_in, const int* in_sizes, int n_in,
                              void* d_out, int out_size, void* d_ws, size_t ws_size,
                              hipStream_t stream)
{
    (void)in_sizes; (void)n_in; (void)out_size; (void)ws_size;
    const int*   seq    = (const int*)  d_in[0];
    const float* incl   = (const float*)d_in[1];
    const float* emb    = (const float*)d_in[2];
    const float* fc1w   = (const float*)d_in[3];
    const float* fc1b   = (const float*)d_in[4];
    const float* fc2w   = (const float*)d_in[5];
    const float* fc2b   = (const float*)d_in[6];
    const float* nscale = (const float*)d_in[7];
    const float* ipw    = (const float*)d_in[8];
    const float* cw     = (const float*)d_in[9];
    const float* cbv    = (const float*)d_in[10];
    const float* xpw    = (const float*)d_in[11];
    const float* dtw    = (const float*)d_in[12];
    const float* dtb    = (const float*)d_in[13];
    const float* alog   = (const float*)d_in[14];
    const float* Dvec   = (const float*)d_in[15];
    const float* opw    = (const float*)d_in[16];
    float* outp = (float*)d_out;

    char* w = (char*)d_ws;
    size_t off = 0;
    auto take = [&](size_t bytes) {
        char* p = w + off; off += (bytes + 255) & ~(size_t)255; return p;
    };
    float* subg  = (float*)take((size_t)MROWS * DMODEL * 4);       // fp32 residual stream
    u16*   zi    = (u16*)  take((size_t)MROWS * DMODEL * 2);       // rmsnorm out (33.5MB)
    u16*   xzb   = (u16*)  take((size_t)MROWS * 2 * DINNER * 2);   // in_proj out (xin|z)
    u16*   xconv = (u16*)  take((size_t)MROWS * DINNER * 2);       // conv+silu out
    u16*   xdbl  = (u16*)  take((size_t)MROWS * 128 * 2);          // x_proj out (pad 128)
    u16*   delta = (u16*)  take((size_t)MROWS * DINNER * 2);       // softplus(dt_proj)
    u16*   ybuf  = (u16*)  take((size_t)MROWS * DINNER * 2);       // scan out (gated)
    u16*   wip   = (u16*)  take((size_t)2 * 2 * DINNER * DMODEL * 2);
    u16*   wop   = (u16*)  take((size_t)2 * DMODEL * DINNER * 2);
    u16*   wxp   = (u16*)  take((size_t)2 * 128 * DINNER * 2);
    u16*   wdt   = (u16*)  take((size_t)2 * DINNER * DTRANK * 2);
    u16*   wfc1  = (u16*)  take((size_t)DMODEL * NFEAT * 2);
    float* part  = (float*)take((size_t)BATCH * 8 * DMODEL * 4);
    float* msump = (float*)take((size_t)BATCH * 8 * 4);
    float* dtsums= (float*)take((size_t)BATCH * NCHUNK * DINNER * 4);  // 2 MB
    u16*   gemb  = (u16*)delta;   // alias: gathered emb consumed before delta written
    float* states= (float*)zi;    // alias: zi dead after in_proj GEMM each layer (same 33.5MB)

    // weight prep (ws re-poisoned every call, so redo each call)
    cvt_bf16_kernel<<<(DMODEL * NFEAT / 4 + 255) / 256, 256, 0, stream>>>(fc1w, wfc1, DMODEL * NFEAT / 4);
    cvt_bf16_kernel<<<(2 * 2 * DINNER * DMODEL / 4 + 255) / 256, 256, 0, stream>>>(ipw, wip, 2 * 2 * DINNER * DMODEL / 4);
    cvt_bf16_kernel<<<(2 * DMODEL * DINNER / 4 + 255) / 256, 256, 0, stream>>>(opw, wop, 2 * DMODEL * DINNER / 4);
    cvt_bf16_kernel<<<(2 * DINNER * DTRANK / 4 + 255) / 256, 256, 0, stream>>>(dtw, wdt, 2 * DINNER * DTRANK / 4);
    pad_xpw_kernel<<<(2 * 128 * DINNER / 4) / 256, 256, 0, stream>>>(xpw, wxp);
    gather_kernel<<<MROWS * (NFEAT / 4) / 256, 256, 0, stream>>>(seq, emb, gemb);

    // subg = gathered_emb @ fc1_w^T + fc1_b   (f32 out)
    gemm_bt<0, 0, 0><<<dim3(MROWS / 128, DMODEL / 128), 256, 0, stream>>>(
        gemb, NFEAT, wfc1, NFEAT, subg, DMODEL, fc1b, NFEAT);

    const int scan_blocks = (BATCH * NCHUNK * DINNER) / 256;   // 2048
    for (int i = 0; i < 2; ++i) {
        const float* al = alog + i * DINNER * DSTATE;
        rmsnorm_kernel<<<MROWS / 4, 256, 0, stream>>>(subg, nscale + i * DMODEL, zi);
        // xz = zi @ in_proj_w^T  (bf16 out, N=2048)
        gemm_bt<1, 0, 0><<<dim3(MROWS / 128, 2 * DINNER / 128), 256, 0, stream>>>(
            zi, DMODEL, wip + (size_t)i * 2 * DINNER * DMODEL, DMODEL,
            xzb, 2 * DINNER, nullptr, DMODEL);
        conv_silu_kernel<<<MROWS * 128 / 256, 256, 0, stream>>>(
            xzb, xzb, cw + i * DINNER * 4, cbv + i * DINNER, xconv);
        // x_dbl = xconv @ x_proj_w^T (N padded to 128)
        gemm_bt<1, 0, 0><<<dim3(MROWS / 128, 1), 256, 0, stream>>>(
            xconv, DINNER, wxp + (size_t)i * 128 * DINNER, DINNER,
            xdbl, 128, nullptr, DINNER);
        // delta = softplus(dt @ dt_proj_w^T + dt_proj_b)  (K=32)
        gemm_bt<1, 0, 1><<<dim3(MROWS / 128, DINNER / 128), 256, 0, stream>>>(
            xdbl, 128, wdt + (size_t)i * DINNER * DTRANK, DTRANK,
            delta, DINNER, dtb + i * DINNER, DTRANK);
        // chunked scan
        scan_p1<<<scan_blocks, 256, 0, stream>>>(delta, xconv, xdbl, al, states, dtsums);
        scan_p2<<<scan_blocks, 256, 0, stream>>>(states, dtsums, al);
        scan_p3<<<scan_blocks, 256, 0, stream>>>(delta, xconv, xzb, xdbl, al,
                                                 Dvec + i * DINNER, states, ybuf);
        // subg += y @ out_proj_w^T  (f32 accumulate)
        gemm_bt<0, 1, 0><<<dim3(MROWS / 128, DMODEL / 128), 256, 0, stream>>>(
            ybuf, DINNER, wop + (size_t)i * DMODEL * DINNER, DINNER,
            subg, DMODEL, nullptr, DINNER);
    }

    pool_partial_kernel<<<dim3(8, BATCH), 256, 0, stream>>>(subg, incl, part, msump);
    fc2_kernel<<<BATCH, 256, 0, stream>>>(part, msump, fc2w, fc2b, outp);
}

// Round 5
// 1596.614 us; speedup vs baseline: 2.4795x; 1.2032x over previous
//
#include <hip/hip_runtime.h>
#include <cstdint>
#include <cstddef>

#define LSEQ   1024
#define BATCH  32
#define NFEAT  512
#define DMODEL 512
#define DINNER 1024
#define DSTATE 16
#define DTRANK 32
#define NCLASS 40
#define MROWS  (BATCH * LSEQ)   // 32768
#define NCHUNK 16
#define CLEN   (LSEQ / NCHUNK)  // 64

typedef unsigned short u16;
typedef __attribute__((ext_vector_type(8))) __bf16 bf16x8;
typedef __attribute__((ext_vector_type(4))) float f32x4;
typedef __attribute__((ext_vector_type(8))) unsigned short u16x8;

__device__ __forceinline__ u16 f2bf(float x) {
    union { float f; unsigned u; } v; v.f = x;
    unsigned r = v.u + 0x7fffu + ((v.u >> 16) & 1u);   // round-to-nearest-even
    return (u16)(r >> 16);
}
__device__ __forceinline__ float bf2f(u16 h) {
    union { unsigned u; float f; } v; v.u = ((unsigned)h) << 16;
    return v.f;
}

// dA[s] = g^(s+1), s=0..15, via 4-deep multiply tree (18 muls, no trans).
__device__ __forceinline__ void pow_dA(float g, float* dA) {
    float p2 = g * g, p4 = p2 * p2, p8 = p4 * p4;
    dA[0] = g;        dA[1] = p2;       dA[2] = p2 * g;   dA[3] = p4;
    dA[4] = p4 * g;   dA[5] = p4 * p2;  dA[6] = p4 * dA[2]; dA[7] = p8;
    dA[8] = p8 * g;   dA[9] = p8 * p2;  dA[10] = p8 * dA[2]; dA[11] = p8 * p4;
    dA[12] = p8 * dA[4]; dA[13] = p8 * dA[5]; dA[14] = p8 * dA[6]; dA[15] = p8 * p8;
}

// unpack 8 bf16 (packed in uint4) -> 8 floats; scalar-friendly (shift/and)
__device__ __forceinline__ void unpack8(uint4 w, float* f) {
    union { unsigned u; float v; } c;
    c.u = w.x << 16;         f[0] = c.v;
    c.u = w.x & 0xffff0000u; f[1] = c.v;
    c.u = w.y << 16;         f[2] = c.v;
    c.u = w.y & 0xffff0000u; f[3] = c.v;
    c.u = w.z << 16;         f[4] = c.v;
    c.u = w.z & 0xffff0000u; f[5] = c.v;
    c.u = w.w << 16;         f[6] = c.v;
    c.u = w.w & 0xffff0000u; f[7] = c.v;
}

#define GLL16(g, l) __builtin_amdgcn_global_load_lds( \
    (__attribute__((address_space(1))) void*)(g),     \
    (__attribute__((address_space(3))) void*)(l), 16, 0, 0)

// ---------------------------------------------------------------------------
// C[M,N] = A[M,K](bf16,lda) * B[N,K](bf16,ldb)^T  (+bias) (+softplus) ;
// OUT_BF16: store bf16; ACCUM: f32 +=. 128x128 tile, BK=32, 256 thr (4 waves).
// ---------------------------------------------------------------------------
template<int OUT_BF16, int ACCUM, int ACT>
__global__ __launch_bounds__(256) void gemm_bt(
    const u16* __restrict__ A, int lda,
    const u16* __restrict__ B, int ldb,
    void* __restrict__ Cv, int ldc,
    const float* __restrict__ bias, int K)
{
    __shared__ __align__(16) u16 As[128 * 32];
    __shared__ __align__(16) u16 Bs[128 * 32];
    const int tid  = threadIdx.x;
    const int m0   = blockIdx.x * 128;
    const int n0   = blockIdx.y * 128;
    const int r0   = tid >> 2;            // staging row (0..63), +64 for job 1
    const int c0   = (tid & 3) << 3;      // staging k-chunk (0,8,16,24)
    const int lane = tid & 63;
    const int wave = tid >> 6;
    const int wr   = (wave >> 1) << 6;    // wave row offset in tile
    const int wc   = (wave & 1) << 6;     // wave col offset in tile
    const int frow = lane & 15;
    const int fk   = (lane >> 4) << 3;
    const int quad = lane >> 4;

    const u16* Ap0 = A + (size_t)(m0 + r0) * lda + c0;
    const u16* Ap1 = Ap0 + (size_t)64 * lda;
    const u16* Bp0 = B + (size_t)(n0 + r0) * ldb + c0;
    const u16* Bp1 = Bp0 + (size_t)64 * ldb;
    u16* lA0 = As + tid * 8;  u16* lA1 = As + (tid + 256) * 8;
    u16* lB0 = Bs + tid * 8;  u16* lB1 = Bs + (tid + 256) * 8;

    f32x4 acc[4][4];
#pragma unroll
    for (int i = 0; i < 4; ++i)
#pragma unroll
        for (int j = 0; j < 4; ++j) acc[i][j] = (f32x4){0.f, 0.f, 0.f, 0.f};

    for (int k0 = 0; k0 < K; k0 += 32) {
        GLL16(Ap0 + k0, lA0);
        GLL16(Ap1 + k0, lA1);
        GLL16(Bp0 + k0, lB0);
        GLL16(Bp1 + k0, lB1);
        __syncthreads();
        bf16x8 af[4], bfr[4];
#pragma unroll
        for (int i = 0; i < 4; ++i) {
            af[i]  = *(const bf16x8*)(As + (wr + i * 16 + frow) * 32 + fk);
            bfr[i] = *(const bf16x8*)(Bs + (wc + i * 16 + frow) * 32 + fk);
        }
#pragma unroll
        for (int i = 0; i < 4; ++i)
#pragma unroll
            for (int j = 0; j < 4; ++j)
                acc[i][j] = __builtin_amdgcn_mfma_f32_16x16x32_bf16(
                    af[i], bfr[j], acc[i][j], 0, 0, 0);
        __syncthreads();
    }

    float bv[4];
#pragma unroll
    for (int j = 0; j < 4; ++j)
        bv[j] = bias ? bias[n0 + wc + j * 16 + frow] : 0.f;

#pragma unroll
    for (int i = 0; i < 4; ++i) {
#pragma unroll
        for (int r = 0; r < 4; ++r) {
            size_t row = (size_t)(m0 + wr + i * 16 + quad * 4 + r);
#pragma unroll
            for (int j = 0; j < 4; ++j) {
                size_t cidx = row * (size_t)ldc + (size_t)(n0 + wc + j * 16 + frow);
                float v = acc[i][j][r] + bv[j];
                if (ACT == 1) v = (v > 15.f) ? v : log1pf(expf(v));  // softplus
                if (OUT_BF16)      ((u16*)Cv)[cidx] = f2bf(v);
                else if (ACCUM)    ((float*)Cv)[cidx] += v;
                else               ((float*)Cv)[cidx] = v;
            }
        }
    }
}

// --------------------------- elementwise / prep ----------------------------

__global__ __launch_bounds__(256) void cvt_bf16_kernel(
    const float* __restrict__ src, u16* __restrict__ dst, int n4)
{
    int i = blockIdx.x * 256 + threadIdx.x;
    if (i >= n4) return;
    float4 v = ((const float4*)src)[i];
    ushort4 o; o.x = f2bf(v.x); o.y = f2bf(v.y); o.z = f2bf(v.z); o.w = f2bf(v.w);
    ((ushort4*)dst)[i] = o;
}

// x_proj_w (2,64,1024) f32 -> (2,128,1024) bf16, rows 64..127 zero
__global__ __launch_bounds__(256) void pad_xpw_kernel(
    const float* __restrict__ src, u16* __restrict__ dst)
{
    int i  = blockIdx.x * 256 + threadIdx.x;   // per float4; total 2*128*1024/4
    int k4 = i & 255;
    int r  = (i >> 8) & 127;
    int l  = i >> 15;
    ushort4 o;
    if (r < 64) {
        float4 v = ((const float4*)(src + ((size_t)l * 64 + r) * DINNER))[k4];
        o.x = f2bf(v.x); o.y = f2bf(v.y); o.z = f2bf(v.z); o.w = f2bf(v.w);
    } else { o.x = 0; o.y = 0; o.z = 0; o.w = 0; }
    ((ushort4*)dst)[i] = o;
}

// gathered_emb[m,:] = bf16(embeddings[sequence[m],:])
__global__ __launch_bounds__(256) void gather_kernel(
    const int* __restrict__ seq, const float* __restrict__ emb, u16* __restrict__ g)
{
    int i   = blockIdx.x * 256 + threadIdx.x;  // per float4; total MROWS*128
    int row = i >> 7, c = i & 127;
    int node = seq[row];
    float4 v = ((const float4*)(emb + (size_t)node * NFEAT))[c];
    ushort4 o; o.x = f2bf(v.x); o.y = f2bf(v.y); o.z = f2bf(v.z); o.w = f2bf(v.w);
    ((ushort4*)g)[i] = o;
}

// zi = scale * x / (||x||/sqrt(512) + 1e-8), one wave per row
__global__ __launch_bounds__(256) void rmsnorm_kernel(
    const float* __restrict__ x, const float* __restrict__ scale, u16* __restrict__ o)
{
    int wave = threadIdx.x >> 6, lane = threadIdx.x & 63;
    size_t row = (size_t)blockIdx.x * 4 + wave;
    const float4* xr = (const float4*)(x + row * DMODEL);
    float4 v0 = xr[lane], v1 = xr[lane + 64];
    float ss = v0.x*v0.x + v0.y*v0.y + v0.z*v0.z + v0.w*v0.w
             + v1.x*v1.x + v1.y*v1.y + v1.z*v1.z + v1.w*v1.w;
#pragma unroll
    for (int off = 32; off; off >>= 1) ss += __shfl_xor(ss, off, 64);
    float inv = 1.f / (sqrtf(ss * (1.f / DMODEL)) + 1e-8f);
    const float4* sc = (const float4*)scale;
    float4 s0 = sc[lane], s1 = sc[lane + 64];
    ushort4 o0, o1;
    o0.x = f2bf(v0.x * s0.x * inv); o0.y = f2bf(v0.y * s0.y * inv);
    o0.z = f2bf(v0.z * s0.z * inv); o0.w = f2bf(v0.w * s0.w * inv);
    o1.x = f2bf(v1.x * s1.x * inv); o1.y = f2bf(v1.y * s1.y * inv);
    o1.z = f2bf(v1.z * s1.z * inv); o1.w = f2bf(v1.w * s1.w * inv);
    ushort4* op = (ushort4*)(o + row * DMODEL);
    op[lane] = o0; op[lane + 64] = o1;
}

// causal depthwise conv (window 4) + bias + silu on x-half; 8 channels/thread,
// u16x8 vector loads. z-half replaced in-place by silu(z).
__global__ __launch_bounds__(256) void conv_silu_kernel(
    const u16* __restrict__ xz, u16* __restrict__ xzm,
    const float* __restrict__ w, const float* __restrict__ cbv,
    u16* __restrict__ xc)
{
    int i  = blockIdx.x * 256 + threadIdx.x;   // MROWS*128 total
    int d0 = (i & 127) << 3;
    int r  = i >> 7;
    int l  = r & (LSEQ - 1);
    const u16* bx = xz + (size_t)r * (2 * DINNER) + d0;
    u16x8 zero{};
    u16x8 t3 = *(const u16x8*)(bx);
    u16x8 t2 = (l >= 1) ? *(const u16x8*)(bx - 2 * DINNER) : zero;
    u16x8 t1 = (l >= 2) ? *(const u16x8*)(bx - 4 * DINNER) : zero;
    u16x8 t0 = (l >= 3) ? *(const u16x8*)(bx - 6 * DINNER) : zero;
    u16x8 zl = *(const u16x8*)(bx + DINNER);
    u16x8 oc, oz;
#pragma unroll
    for (int c = 0; c < 8; ++c) {
        float4 wc = ((const float4*)w)[d0 + c];
        float acc = cbv[d0 + c]
                  + wc.x * bf2f(t0[c]) + wc.y * bf2f(t1[c])
                  + wc.z * bf2f(t2[c]) + wc.w * bf2f(t3[c]);
        oc[c] = f2bf(acc / (1.f + expf(-acc)));
        float zv = bf2f(zl[c]);
        oz[c] = f2bf(zv / (1.f + expf(-zv)));
    }
    *(u16x8*)(xc + (size_t)r * DINNER + d0) = oc;
    *(u16x8*)(xzm + (size_t)r * (2 * DINNER) + DINNER + d0) = oz;
}

// ---------------------------------------------------------------------------
// Chunked selective scan, v3: block -> (b, k, d-tile) from blockIdx ONLY, so
// the B/C row address is wave-uniform (compiler can scalarize to s_load).
// Software-pipelined: prefetch j+1's dt/x/z + B/C while computing j.
// S4D fast path (dA[s] = g^(s+1)) with generic fallback.
// NOTE: prefetch overreads <=1 row past chunk end - lands in the next ws
// buffer (allocated), value never used.
// ---------------------------------------------------------------------------
__device__ __forceinline__ int detect_s4d(const float* a2) {
    int fast = 1;
#pragma unroll
    for (int s = 1; s < DSTATE; ++s)
        fast &= (__builtin_fabsf(a2[s] - (float)(s + 1) * a2[0]) <=
                 1e-4f * (float)(s + 1) * __builtin_fabsf(a2[0]) + 1e-6f);
    return fast;
}

__global__ __launch_bounds__(256) void scan_p1(
    const u16* __restrict__ delta, const u16* __restrict__ xconv,
    const u16* __restrict__ xdbl, const float* __restrict__ alog,
    float* __restrict__ states, float* __restrict__ dtsums)
{
    const int bid = blockIdx.x;
    const int d0  = (bid & 3) << 8;
    const int k   = (bid >> 2) & (NCHUNK - 1);
    const int b   = bid >> 6;
    const int d   = d0 + threadIdx.x;

    float a2[DSTATE];
#pragma unroll
    for (int s = 0; s < DSTATE; ++s)
        a2[s] = -expf(alog[d * DSTATE + s]) * 1.44269504f;
    const int fastA = detect_s4d(a2);
    const float ab = a2[0];

    float h[DSTATE];
#pragma unroll
    for (int s = 0; s < DSTATE; ++s) h[s] = 0.f;
    float dtsum = 0.f;

    const size_t r0 = (size_t)b * LSEQ + (size_t)k * CLEN;
    const u16* pd = delta + r0 * DINNER + d;
    const u16* px = xconv + r0 * DINNER + d;
    const unsigned* pB = (const unsigned*)(xdbl + r0 * 128) + 16;  // uniform

    float dt = bf2f(*pd), xv = bf2f(*px);
    uint4 wB  = *(const uint4*)(pB);
    uint4 wB2 = *(const uint4*)(pB + 4);

    if (fastA) {
        for (int j = 0; j < CLEN; ++j) {
            pd += DINNER; px += DINNER; pB += 64;
            float dt_n = bf2f(*pd), xv_n = bf2f(*px);
            uint4 wBn  = *(const uint4*)(pB);
            uint4 wB2n = *(const uint4*)(pB + 4);
            float dx = dt * xv;
            dtsum += dt;
            float dA[DSTATE];
            pow_dA(__builtin_amdgcn_exp2f(dt * ab), dA);
            float Bv[DSTATE];
            unpack8(wB, Bv); unpack8(wB2, Bv + 8);
#pragma unroll
            for (int s = 0; s < DSTATE; ++s)
                h[s] = __builtin_fmaf(h[s], dA[s], dx * Bv[s]);
            dt = dt_n; xv = xv_n; wB = wBn; wB2 = wB2n;
        }
    } else {
        for (int j = 0; j < CLEN; ++j) {
            pd += DINNER; px += DINNER; pB += 64;
            float dt_n = bf2f(*pd), xv_n = bf2f(*px);
            uint4 wBn  = *(const uint4*)(pB);
            uint4 wB2n = *(const uint4*)(pB + 4);
            float dx = dt * xv;
            dtsum += dt;
            float Bv[DSTATE];
            unpack8(wB, Bv); unpack8(wB2, Bv + 8);
#pragma unroll
            for (int s = 0; s < DSTATE; ++s)
                h[s] = __builtin_fmaf(h[s], __builtin_amdgcn_exp2f(dt * a2[s]),
                                      dx * Bv[s]);
            dt = dt_n; xv = xv_n; wB = wBn; wB2 = wB2n;
        }
    }

    size_t t = (size_t)(b * NCHUNK + k) * DINNER + d;
    f32x4* st = (f32x4*)(states + t * DSTATE);
#pragma unroll
    for (int q = 0; q < 4; ++q)
        st[q] = (f32x4){h[q * 4], h[q * 4 + 1], h[q * 4 + 2], h[q * 4 + 3]};
    dtsums[t] = dtsum;
}

__global__ __launch_bounds__(256) void scan_p2(
    float* __restrict__ states, const float* __restrict__ dtsums,
    const float* __restrict__ alog)
{
    int t = blockIdx.x * 256 + threadIdx.x;   // 0 .. B*DINNER*DSTATE-1
    int s = t & (DSTATE - 1);
    int d = (t >> 4) & (DINNER - 1);
    int b = t >> 14;
    float a2 = -expf(alog[d * DSTATE + s]) * 1.44269504f;
    float H = 0.f;
    for (int k = 0; k < NCHUNK; ++k) {
        size_t ci = ((size_t)b * NCHUNK + k) * DINNER + d;
        size_t idx = ci * DSTATE + s;
        float hk = states[idx];
        float P = __builtin_amdgcn_exp2f(a2 * dtsums[ci]);
        states[idx] = H;                 // exclusive incoming state for chunk k
        H = hk + P * H;
    }
}

__global__ __launch_bounds__(256) void scan_p3(
    const u16* __restrict__ delta, const u16* __restrict__ xconv,
    const u16* __restrict__ zsil, const u16* __restrict__ xdbl,
    const float* __restrict__ alog, const float* __restrict__ Dvec,
    const float* __restrict__ states, u16* __restrict__ ybuf)
{
    const int bid = blockIdx.x;
    const int d0  = (bid & 3) << 8;
    const int k   = (bid >> 2) & (NCHUNK - 1);
    const int b   = bid >> 6;
    const int d   = d0 + threadIdx.x;

    float a2[DSTATE];
#pragma unroll
    for (int s = 0; s < DSTATE; ++s)
        a2[s] = -expf(alog[d * DSTATE + s]) * 1.44269504f;
    const int fastA = detect_s4d(a2);
    const float ab = a2[0];
    const float Dd = Dvec[d];

    float h[DSTATE];
    size_t t = (size_t)(b * NCHUNK + k) * DINNER + d;
    const f32x4* st = (const f32x4*)(states + t * DSTATE);
#pragma unroll
    for (int q = 0; q < 4; ++q) {
        f32x4 v = st[q];
        h[q * 4] = v[0]; h[q * 4 + 1] = v[1]; h[q * 4 + 2] = v[2]; h[q * 4 + 3] = v[3];
    }

    const size_t r0 = (size_t)b * LSEQ + (size_t)k * CLEN;
    const u16* pd = delta + r0 * DINNER + d;
    const u16* px = xconv + r0 * DINNER + d;
    const u16* pz = zsil + r0 * (2 * DINNER) + DINNER + d;
    const unsigned* pB = (const unsigned*)(xdbl + r0 * 128) + 16;  // uniform
    u16* py = ybuf + r0 * DINNER + d;

    float dt = bf2f(*pd), xv = bf2f(*px), zs = bf2f(*pz);
    uint4 wB  = *(const uint4*)(pB);
    uint4 wB2 = *(const uint4*)(pB + 4);
    uint4 wC  = *(const uint4*)(pB + 8);
    uint4 wC2 = *(const uint4*)(pB + 12);

    if (fastA) {
        for (int j = 0; j < CLEN; ++j) {
            pd += DINNER; px += DINNER; pz += 2 * DINNER; pB += 64;
            float dt_n = bf2f(*pd), xv_n = bf2f(*px), zs_n = bf2f(*pz);
            uint4 wBn  = *(const uint4*)(pB);
            uint4 wB2n = *(const uint4*)(pB + 4);
            uint4 wCn  = *(const uint4*)(pB + 8);
            uint4 wC2n = *(const uint4*)(pB + 12);
            float dx = dt * xv;
            float dA[DSTATE];
            pow_dA(__builtin_amdgcn_exp2f(dt * ab), dA);
            float Bv[DSTATE], Cv[DSTATE];
            unpack8(wB, Bv); unpack8(wB2, Bv + 8);
            unpack8(wC, Cv); unpack8(wC2, Cv + 8);
            float y0 = 0.f, y1 = 0.f, y2 = 0.f, y3 = 0.f;
#pragma unroll
            for (int s = 0; s < DSTATE; ++s)
                h[s] = __builtin_fmaf(h[s], dA[s], dx * Bv[s]);
#pragma unroll
            for (int s = 0; s < DSTATE; s += 4) {
                y0 = __builtin_fmaf(h[s],     Cv[s],     y0);
                y1 = __builtin_fmaf(h[s + 1], Cv[s + 1], y1);
                y2 = __builtin_fmaf(h[s + 2], Cv[s + 2], y2);
                y3 = __builtin_fmaf(h[s + 3], Cv[s + 3], y3);
            }
            float yv = ((y0 + y1) + (y2 + y3)) + Dd * xv;
            *py = f2bf(yv * zs); py += DINNER;
            dt = dt_n; xv = xv_n; zs = zs_n;
            wB = wBn; wB2 = wB2n; wC = wCn; wC2 = wC2n;
        }
    } else {
        for (int j = 0; j < CLEN; ++j) {
            pd += DINNER; px += DINNER; pz += 2 * DINNER; pB += 64;
            float dt_n = bf2f(*pd), xv_n = bf2f(*px), zs_n = bf2f(*pz);
            uint4 wBn  = *(const uint4*)(pB);
            uint4 wB2n = *(const uint4*)(pB + 4);
            uint4 wCn  = *(const uint4*)(pB + 8);
            uint4 wC2n = *(const uint4*)(pB + 12);
            float dx = dt * xv;
            float Bv[DSTATE], Cv[DSTATE];
            unpack8(wB, Bv); unpack8(wB2, Bv + 8);
            unpack8(wC, Cv); unpack8(wC2, Cv + 8);
            float y0 = 0.f, y1 = 0.f, y2 = 0.f, y3 = 0.f;
#pragma unroll
            for (int s = 0; s < DSTATE; ++s) {
                h[s] = __builtin_fmaf(h[s], __builtin_amdgcn_exp2f(dt * a2[s]),
                                      dx * Bv[s]);
            }
#pragma unroll
            for (int s = 0; s < DSTATE; s += 4) {
                y0 = __builtin_fmaf(h[s],     Cv[s],     y0);
                y1 = __builtin_fmaf(h[s + 1], Cv[s + 1], y1);
                y2 = __builtin_fmaf(h[s + 2], Cv[s + 2], y2);
                y3 = __builtin_fmaf(h[s + 3], Cv[s + 3], y3);
            }
            float yv = ((y0 + y1) + (y2 + y3)) + Dd * xv;
            *py = f2bf(yv * zs); py += DINNER;
            dt = dt_n; xv = xv_n; zs = zs_n;
            wB = wBn; wB2 = wB2n; wC = wCn; wC2 = wC2n;
        }
    }
}

// masked-mean partials: grid (8 chunks, 32 b)
__global__ __launch_bounds__(256) void pool_partial_kernel(
    const float* __restrict__ subg, const float* __restrict__ incl,
    float* __restrict__ part, float* __restrict__ msump)
{
    int chunk = blockIdx.x, b = blockIdx.y, tid = threadIdx.x;
    float a0 = 0.f, a1 = 0.f, ms = 0.f;
    for (int l0 = 0; l0 < 128; ++l0) {
        int l = chunk * 128 + l0;
        float m = incl[b * LSEQ + l];
        const float* row = subg + ((size_t)b * LSEQ + l) * DMODEL;
        a0 += m * row[tid];
        a1 += m * row[tid + 256];
        ms += m;
    }
    int pi = (b * 8 + chunk) * DMODEL;
    part[pi + tid] = a0;
    part[pi + tid + 256] = a1;
    if (tid == 0) msump[b * 8 + chunk] = ms;
}

__global__ __launch_bounds__(256) void fc2_kernel(
    const float* __restrict__ part, const float* __restrict__ msump,
    const float* __restrict__ fc2w, const float* __restrict__ fc2b,
    float* __restrict__ out)
{
    int b = blockIdx.x, tid = threadIdx.x;
    __shared__ float pooled[DMODEL];
    float s0 = 0.f, s1 = 0.f, ms = 0.f;
#pragma unroll
    for (int c = 0; c < 8; ++c) {
        s0 += part[(b * 8 + c) * DMODEL + tid];
        s1 += part[(b * 8 + c) * DMODEL + tid + 256];
        ms += msump[b * 8 + c];
    }
    float inv = 1.f / (ms + 1e-5f);
    pooled[tid] = s0 * inv; pooled[tid + 256] = s1 * inv;
    __syncthreads();
    int wave = tid >> 6, lane = tid & 63;
    for (int c = wave; c < NCLASS; c += 4) {
        float s = 0.f;
#pragma unroll
        for (int k = lane; k < DMODEL; k += 64) s += pooled[k] * fc2w[c * DMODEL + k];
#pragma unroll
        for (int off = 32; off; off >>= 1) s += __shfl_xor(s, off, 64);
        if (lane == 0) out[b * NCLASS + c] = s + fc2b[c];
    }
}

// ---------------------------------------------------------------------------

extern "C" void kernel_launch(void* const* d_in, const int* in_sizes, int n_in,
                              void* d_out, int out_size, void* d_ws, size_t ws_size,
                              hipStream_t stream)
{
    (void)in_sizes; (void)n_in; (void)out_size; (void)ws_size;
    const int*   seq    = (const int*)  d_in[0];
    const float* incl   = (const float*)d_in[1];
    const float* emb    = (const float*)d_in[2];
    const float* fc1w   = (const float*)d_in[3];
    const float* fc1b   = (const float*)d_in[4];
    const float* fc2w   = (const float*)d_in[5];
    const float* fc2b   = (const float*)d_in[6];
    const float* nscale = (const float*)d_in[7];
    const float* ipw    = (const float*)d_in[8];
    const float* cw     = (const float*)d_in[9];
    const float* cbv    = (const float*)d_in[10];
    const float* xpw    = (const float*)d_in[11];
    const float* dtw    = (const float*)d_in[12];
    const float* dtb    = (const float*)d_in[13];
    const float* alog   = (const float*)d_in[14];
    const float* Dvec   = (const float*)d_in[15];
    const float* opw    = (const float*)d_in[16];
    float* outp = (float*)d_out;

    char* w = (char*)d_ws;
    size_t off = 0;
    auto take = [&](size_t bytes) {
        char* p = w + off; off += (bytes + 255) & ~(size_t)255; return p;
    };
    float* subg  = (float*)take((size_t)MROWS * DMODEL * 4);       // fp32 residual stream
    u16*   zi    = (u16*)  take((size_t)MROWS * DMODEL * 2);       // rmsnorm out (33.5MB)
    u16*   xzb   = (u16*)  take((size_t)MROWS * 2 * DINNER * 2);   // in_proj out (xin|z)
    u16*   xconv = (u16*)  take((size_t)MROWS * DINNER * 2);       // conv+silu out
    u16*   xdbl  = (u16*)  take((size_t)MROWS * 128 * 2);          // x_proj out (pad 128)
    u16*   delta = (u16*)  take((size_t)MROWS * DINNER * 2);       // softplus(dt_proj)
    u16*   ybuf  = (u16*)  take((size_t)MROWS * DINNER * 2);       // scan out (gated)
    u16*   wip   = (u16*)  take((size_t)2 * 2 * DINNER * DMODEL * 2);
    u16*   wop   = (u16*)  take((size_t)2 * DMODEL * DINNER * 2);
    u16*   wxp   = (u16*)  take((size_t)2 * 128 * DINNER * 2);
    u16*   wdt   = (u16*)  take((size_t)2 * DINNER * DTRANK * 2);
    u16*   wfc1  = (u16*)  take((size_t)DMODEL * NFEAT * 2);
    float* part  = (float*)take((size_t)BATCH * 8 * DMODEL * 4);
    float* msump = (float*)take((size_t)BATCH * 8 * 4);
    float* dtsums= (float*)take((size_t)BATCH * NCHUNK * DINNER * 4);  // 2 MB
    u16*   gemb  = (u16*)delta;   // alias: gathered emb consumed before delta written
    float* states= (float*)zi;    // alias: zi dead after in_proj GEMM each layer (same 33.5MB)

    // weight prep (ws re-poisoned every call, so redo each call)
    cvt_bf16_kernel<<<(DMODEL * NFEAT / 4 + 255) / 256, 256, 0, stream>>>(fc1w, wfc1, DMODEL * NFEAT / 4);
    cvt_bf16_kernel<<<(2 * 2 * DINNER * DMODEL / 4 + 255) / 256, 256, 0, stream>>>(ipw, wip, 2 * 2 * DINNER * DMODEL / 4);
    cvt_bf16_kernel<<<(2 * DMODEL * DINNER / 4 + 255) / 256, 256, 0, stream>>>(opw, wop, 2 * DMODEL * DINNER / 4);
    cvt_bf16_kernel<<<(2 * DINNER * DTRANK / 4 + 255) / 256, 256, 0, stream>>>(dtw, wdt, 2 * DINNER * DTRANK / 4);
    pad_xpw_kernel<<<(2 * 128 * DINNER / 4) / 256, 256, 0, stream>>>(xpw, wxp);
    gather_kernel<<<MROWS * (NFEAT / 4) / 256, 256, 0, stream>>>(seq, emb, gemb);

    // subg = gathered_emb @ fc1_w^T + fc1_b   (f32 out)
    gemm_bt<0, 0, 0><<<dim3(MROWS / 128, DMODEL / 128), 256, 0, stream>>>(
        gemb, NFEAT, wfc1, NFEAT, subg, DMODEL, fc1b, NFEAT);

    const int scan_blocks = (BATCH * NCHUNK * DINNER) / 256;   // 2048
    for (int i = 0; i < 2; ++i) {
        const float* al = alog + i * DINNER * DSTATE;
        rmsnorm_kernel<<<MROWS / 4, 256, 0, stream>>>(subg, nscale + i * DMODEL, zi);
        // xz = zi @ in_proj_w^T  (bf16 out, N=2048)
        gemm_bt<1, 0, 0><<<dim3(MROWS / 128, 2 * DINNER / 128), 256, 0, stream>>>(
            zi, DMODEL, wip + (size_t)i * 2 * DINNER * DMODEL, DMODEL,
            xzb, 2 * DINNER, nullptr, DMODEL);
        conv_silu_kernel<<<MROWS * 128 / 256, 256, 0, stream>>>(
            xzb, xzb, cw + i * DINNER * 4, cbv + i * DINNER, xconv);
        // x_dbl = xconv @ x_proj_w^T (N padded to 128)
        gemm_bt<1, 0, 0><<<dim3(MROWS / 128, 1), 256, 0, stream>>>(
            xconv, DINNER, wxp + (size_t)i * 128 * DINNER, DINNER,
            xdbl, 128, nullptr, DINNER);
        // delta = softplus(dt @ dt_proj_w^T + dt_proj_b)  (K=32)
        gemm_bt<1, 0, 1><<<dim3(MROWS / 128, DINNER / 128), 256, 0, stream>>>(
            xdbl, 128, wdt + (size_t)i * DINNER * DTRANK, DTRANK,
            delta, DINNER, dtb + i * DINNER, DTRANK);
        // chunked scan
        scan_p1<<<scan_blocks, 256, 0, stream>>>(delta, xconv, xdbl, al, states, dtsums);
        scan_p2<<<scan_blocks, 256, 0, stream>>>(states, dtsums, al);
        scan_p3<<<scan_blocks, 256, 0, stream>>>(delta, xconv, xzb, xdbl, al,
                                                 Dvec + i * DINNER, states, ybuf);
        // subg += y @ out_proj_w^T  (f32 accumulate)
        gemm_bt<0, 1, 0><<<dim3(MROWS / 128, DMODEL / 128), 256, 0, stream>>>(
            ybuf, DINNER, wop + (size_t)i * DMODEL * DINNER, DINNER,
            subg, DMODEL, nullptr, DINNER);
    }

    pool_partial_kernel<<<dim3(8, BATCH), 256, 0, stream>>>(subg, incl, part, msump);
    fc2_kernel<<<BATCH, 256, 0, stream>>>(part, msump, fc2w, fc2b, outp);
}